// Round 3
// baseline (326.395 us; speedup 1.0000x reference)
//
#include <hip/hip_runtime.h>
#include <hip/hip_bf16.h>

#define NRAYS 8192
#define TS    256

typedef const float* fpp;

__device__ __forceinline__ float waveAllSum(float v) {
#pragma unroll
  for (int off = 32; off > 0; off >>= 1) v += __shfl_xor(v, off, 64);
  return v;
}

// output layout (flat, fp32):
// image  [8192,3]   @ 0
// depth  [8192]     @ 24576
// dvar   [8192]     @ 32768
// coord  [8192,3]   @ 40960
// rgbs   [8192,256,3] @ 65536
// clipf  [8192,32]  @ 6356992
#define OFF_IMG   0
#define OFF_DEPTH 24576
#define OFF_VAR   32768
#define OFF_COORD 40960
#define OFF_RGBS  65536
#define OFF_CLIP  6356992

__global__ __launch_bounds__(256) void nerf_kernel(
    fpp rays_o, fpp rays_d, fpp dnorms,
    fpp Wd1, fpp bd1, fpp Wd2, fpp bd2,
    fpp Wc1, fpp bc1, fpp Wc2, fpp bc2,
    fpp Wk1, fpp bk1, fpp Wk2, fpp bk2,
    float* out)
{
  // LDS weight staging, transposed + padded for float4 reads
  __shared__ __align__(16) float sD1[64 * 4];    // [j][{w0,w1,w2,bias}]
  __shared__ __align__(16) float sD2[64 * 16];   // row-major copy of Wd2
  __shared__ __align__(16) float sBd2[16];
  __shared__ __align__(16) float sC1[64 * 20];   // [j][{Wc1[0..17][j], bc1[j], 0}]
  __shared__ __align__(16) float sC2[64 * 4];    // [j][{Wc2[j][0..2], 0}]
  __shared__ __align__(16) float sBc2[4];
  __shared__ __align__(16) float sK1[64 * 20];   // [j][{Wk1[0..15][j], bk1[j], 0,0,0}]
  __shared__ __align__(16) float sK2[64 * 32];   // row-major copy of Wk2
  __shared__ __align__(16) float sBk2[32];

  const int tid = threadIdx.x;

  {
    int i = tid; // 256 threads
    { int j = i >> 2, c = i & 3; sD1[i] = (c < 3) ? Wd1[c * 64 + j] : bd1[j]; }
    for (int k = tid; k < 1024; k += 256) sD2[k] = Wd2[k];
    if (tid < 16) sBd2[tid] = bd2[tid];
    for (int k = tid; k < 1280; k += 256) {
      int j = k / 20, c = k - j * 20;
      sC1[k] = (c < 18) ? Wc1[c * 64 + j] : ((c == 18) ? bc1[j] : 0.f);
    }
    { int j = i >> 2, c = i & 3; sC2[i] = (c < 3) ? Wc2[j * 3 + c] : 0.f; }
    if (tid < 4) sBc2[tid] = (tid < 3) ? bc2[tid] : 0.f;
    for (int k = tid; k < 1280; k += 256) {
      int j = k / 20, c = k - j * 20;
      sK1[k] = (c < 16) ? Wk1[c * 64 + j] : ((c == 16) ? bk1[j] : 0.f);
    }
    for (int k = tid; k < 2048; k += 256) sK2[k] = Wk2[k];
    if (tid < 32) sBk2[tid] = bk2[tid];
  }
  __syncthreads();

  const int wave = tid >> 6;
  const int lane = tid & 63;
  const int ray  = blockIdx.x * 4 + wave;

  const float ox = rays_o[ray * 3 + 0];
  const float oy = rays_o[ray * 3 + 1];
  const float oz = rays_o[ray * 3 + 2];
  const float dx = rays_d[ray * 3 + 0];
  const float dy = rays_d[ray * 3 + 1];
  const float dz = rays_d[ray * 3 + 2];
  const float dn = dnorms[ray];

  // AABB near/far
  const float ixr = 1.f / dx, iyr = 1.f / dy, izr = 1.f / dz;
  float t1x = (-1.f - ox) * ixr, t2x = (1.f - ox) * ixr;
  float t1y = (-1.f - oy) * iyr, t2y = (1.f - oy) * iyr;
  float t1z = (-1.f - oz) * izr, t2z = (1.f - oz) * izr;
  float nearv = fmaxf(fmaxf(fminf(t1x, t2x), fminf(t1y, t2y)), fminf(t1z, t2z));
  nearv = fmaxf(nearv, 0.2f);
  float farv = fminf(fminf(fmaxf(t1x, t2x), fmaxf(t1y, t2y)), fmaxf(t1z, t2z));
  farv = fmaxf(farv, nearv + 0.0001f);
  const float span = farv - nearv;

  float z[4], sigma[4], geo[4][15];

  // ---------- Pass A: density MLP (3 -> 64 -> 16) ----------
  {
    float xs[4], ys[4], zs[4];
    float h2[4][16];
#pragma unroll
    for (int i = 0; i < 4; i++) {
      int t = lane * 4 + i;
      z[i]  = nearv + span * ((float)t * (1.f / 255.f));
      xs[i] = fminf(fmaxf(fmaf(dx, z[i], ox), -1.f), 1.f);
      ys[i] = fminf(fmaxf(fmaf(dy, z[i], oy), -1.f), 1.f);
      zs[i] = fminf(fmaxf(fmaf(dz, z[i], oz), -1.f), 1.f);
#pragma unroll
      for (int k = 0; k < 16; k++) h2[i][k] = sBd2[k];
    }
    for (int j = 0; j < 64; j++) {
      const float4 d1 = *(const float4*)&sD1[j * 4];
      const float4 w0 = *(const float4*)&sD2[j * 16 + 0];
      const float4 w1 = *(const float4*)&sD2[j * 16 + 4];
      const float4 w2 = *(const float4*)&sD2[j * 16 + 8];
      const float4 w3 = *(const float4*)&sD2[j * 16 + 12];
#pragma unroll
      for (int i = 0; i < 4; i++) {
        float h = fmaf(xs[i], d1.x, fmaf(ys[i], d1.y, fmaf(zs[i], d1.z, d1.w)));
        h = fmaxf(h, 0.f);
        h2[i][0]  = fmaf(h, w0.x, h2[i][0]);  h2[i][1]  = fmaf(h, w0.y, h2[i][1]);
        h2[i][2]  = fmaf(h, w0.z, h2[i][2]);  h2[i][3]  = fmaf(h, w0.w, h2[i][3]);
        h2[i][4]  = fmaf(h, w1.x, h2[i][4]);  h2[i][5]  = fmaf(h, w1.y, h2[i][5]);
        h2[i][6]  = fmaf(h, w1.z, h2[i][6]);  h2[i][7]  = fmaf(h, w1.w, h2[i][7]);
        h2[i][8]  = fmaf(h, w2.x, h2[i][8]);  h2[i][9]  = fmaf(h, w2.y, h2[i][9]);
        h2[i][10] = fmaf(h, w2.z, h2[i][10]); h2[i][11] = fmaf(h, w2.w, h2[i][11]);
        h2[i][12] = fmaf(h, w3.x, h2[i][12]); h2[i][13] = fmaf(h, w3.y, h2[i][13]);
        h2[i][14] = fmaf(h, w3.z, h2[i][14]); h2[i][15] = fmaf(h, w3.w, h2[i][15]);
      }
    }
#pragma unroll
    for (int i = 0; i < 4; i++) {
      sigma[i] = expf(h2[i][0]);
#pragma unroll
      for (int k = 0; k < 15; k++) geo[i][k] = h2[i][k + 1];
    }
  }

  // ---------- transmittance scan ----------
  float alpha[4], w[4], wm[4];
  {
    float v[4], m[4];
#pragma unroll
    for (int i = 0; i < 4; i++) {
      int t = lane * 4 + i;
      float delta = (t < 255) ? span * (1.f / 255.f) : span * (1.f / 256.f);
      alpha[i] = 1.f - expf(-delta * sigma[i]);
      v[i] = 1.f - alpha[i] + 1e-15f;
    }
    m[0] = 1.f; m[1] = v[0]; m[2] = m[1] * v[1]; m[3] = m[2] * v[2];
    float P = m[3] * v[3];
    float ip = P;
#pragma unroll
    for (int off = 1; off < 64; off <<= 1) {
      float u = __shfl_up(ip, off, 64);
      if (lane >= off) ip *= u;
    }
    float E = __shfl_up(ip, 1, 64);
    if (lane == 0) E = 1.f;
#pragma unroll
    for (int i = 0; i < 4; i++) {
      float tr = E * m[i];
      w[i]  = alpha[i] * tr;
      wm[i] = (w[i] > 0.0001f) ? w[i] : 0.f;
    }
  }

  // ---------- Pass B1: color MLP (18 -> 64 -> 3) + per-sample outputs ----------
  float img0 = 0.f, img1 = 0.f, img2 = 0.f;
  float cx = 0.f, cy = 0.f, cz = 0.f;
  float ws = 0.f, swz = 0.f;
  {
    float rgb[4][3];
#pragma unroll
    for (int i = 0; i < 4; i++) { rgb[i][0] = sBc2[0]; rgb[i][1] = sBc2[1]; rgb[i][2] = sBc2[2]; }
    for (int j = 0; j < 64; j++) {
      const float4* C1 = (const float4*)&sC1[j * 20];
      const float4 a0 = C1[0], a1 = C1[1], a2 = C1[2], a3 = C1[3], a4 = C1[4];
      const float4 cw = *(const float4*)&sC2[j * 4];
#pragma unroll
      for (int i = 0; i < 4; i++) {
        float h = a4.z; // bias
        h = fmaf(dx, a0.x, h); h = fmaf(dy, a0.y, h); h = fmaf(dz, a0.z, h);
        h = fmaf(geo[i][0], a0.w, h);
        h = fmaf(geo[i][1], a1.x, h); h = fmaf(geo[i][2], a1.y, h);
        h = fmaf(geo[i][3], a1.z, h); h = fmaf(geo[i][4], a1.w, h);
        h = fmaf(geo[i][5], a2.x, h); h = fmaf(geo[i][6], a2.y, h);
        h = fmaf(geo[i][7], a2.z, h); h = fmaf(geo[i][8], a2.w, h);
        h = fmaf(geo[i][9], a3.x, h); h = fmaf(geo[i][10], a3.y, h);
        h = fmaf(geo[i][11], a3.z, h); h = fmaf(geo[i][12], a3.w, h);
        h = fmaf(geo[i][13], a4.x, h); h = fmaf(geo[i][14], a4.y, h);
        h = fmaxf(h, 0.f);
        rgb[i][0] = fmaf(h, cw.x, rgb[i][0]);
        rgb[i][1] = fmaf(h, cw.y, rgb[i][1]);
        rgb[i][2] = fmaf(h, cw.z, rgb[i][2]);
      }
    }
#pragma unroll
    for (int i = 0; i < 4; i++) {
      const int t = lane * 4 + i;
      const bool mk = (w[i] > 0.0001f);
      float s0 = 1.f / (1.f + expf(-rgb[i][0]));
      float s1 = 1.f / (1.f + expf(-rgb[i][1]));
      float s2 = 1.f / (1.f + expf(-rgb[i][2]));
      s0 = mk ? s0 : 0.f; s1 = mk ? s1 : 0.f; s2 = mk ? s2 : 0.f;
      const long ro = (long)OFF_RGBS + ((long)ray * TS + t) * 3;
      out[ro + 0] = s0; out[ro + 1] = s1; out[ro + 2] = s2;
      img0 = fmaf(wm[i], s0, img0);
      img1 = fmaf(wm[i], s1, img1);
      img2 = fmaf(wm[i], s2, img2);
      float xc = fminf(fmaxf(fmaf(dx, z[i], ox), -1.f), 1.f);
      float yc = fminf(fmaxf(fmaf(dy, z[i], oy), -1.f), 1.f);
      float zc = fminf(fmaxf(fmaf(dz, z[i], oz), -1.f), 1.f);
      cx = fmaf(wm[i], xc, cx); cy = fmaf(wm[i], yc, cy); cz = fmaf(wm[i], zc, cz);
      ws += wm[i];
      swz = fmaf(wm[i], z[i], swz);
    }
  }

  // ---------- per-ray reductions ----------
  ws   = waveAllSum(ws);
  swz  = waveAllSum(swz);
  img0 = waveAllSum(img0); img1 = waveAllSum(img1); img2 = waveAllSum(img2);
  cx   = waveAllSum(cx);   cy   = waveAllSum(cy);   cz   = waveAllSum(cz);
  const float depth = swz / dn;
  float var = 0.f;
#pragma unroll
  for (int i = 0; i < 4; i++) {
    float dd = depth - z[i] / dn;
    var = fmaf(wm[i], dd * dd, var);
  }
  var = waveAllSum(var);

  // ---------- Pass B2: clip MLP (16 -> 64), hoisted 64x32 to per-ray ----------
  float clipf[32];
#pragma unroll
  for (int k = 0; k < 32; k++) clipf[k] = 0.f;
  for (int j = 0; j < 64; j++) {
    const float4* K1 = (const float4*)&sK1[j * 20];
    const float4 b0 = K1[0], b1 = K1[1], b2 = K1[2], b3 = K1[3], b4 = K1[4];
    float gj = 0.f;
#pragma unroll
    for (int i = 0; i < 4; i++) {
      float h = b4.x; // bias
      h = fmaf(geo[i][0], b0.x, h);  h = fmaf(geo[i][1], b0.y, h);
      h = fmaf(geo[i][2], b0.z, h);  h = fmaf(geo[i][3], b0.w, h);
      h = fmaf(geo[i][4], b1.x, h);  h = fmaf(geo[i][5], b1.y, h);
      h = fmaf(geo[i][6], b1.z, h);  h = fmaf(geo[i][7], b1.w, h);
      h = fmaf(geo[i][8], b2.x, h);  h = fmaf(geo[i][9], b2.y, h);
      h = fmaf(geo[i][10], b2.z, h); h = fmaf(geo[i][11], b2.w, h);
      h = fmaf(geo[i][12], b3.x, h); h = fmaf(geo[i][13], b3.y, h);
      h = fmaf(geo[i][14], b3.z, h); h = fmaf(sigma[i], b3.w, h);
      h = fmaxf(h, 0.f);
      gj = fmaf(wm[i], h, gj);
    }
    gj = waveAllSum(gj); // uniform across lanes now
    const float4* K2 = (const float4*)&sK2[j * 32];
#pragma unroll
    for (int q = 0; q < 8; q++) {
      const float4 kk = K2[q];
      clipf[q * 4 + 0] = fmaf(gj, kk.x, clipf[q * 4 + 0]);
      clipf[q * 4 + 1] = fmaf(gj, kk.y, clipf[q * 4 + 1]);
      clipf[q * 4 + 2] = fmaf(gj, kk.z, clipf[q * 4 + 2]);
      clipf[q * 4 + 3] = fmaf(gj, kk.w, clipf[q * 4 + 3]);
    }
  }

  // ---------- writes (lane 0) ----------
  if (lane == 0) {
    out[OFF_IMG + ray * 3 + 0] = img0 + (1.f - ws);
    out[OFF_IMG + ray * 3 + 1] = img1 + (1.f - ws);
    out[OFF_IMG + ray * 3 + 2] = img2 + (1.f - ws);
    out[OFF_DEPTH + ray] = depth;
    out[OFF_VAR + ray]   = var;
    out[OFF_COORD + ray * 3 + 0] = cx;
    out[OFF_COORD + ray * 3 + 1] = cy;
    out[OFF_COORD + ray * 3 + 2] = cz;
#pragma unroll
    for (int k = 0; k < 32; k++)
      out[OFF_CLIP + ray * 32 + k] = clipf[k] + ws * sBk2[k];
  }
}

extern "C" void kernel_launch(void* const* d_in, const int* in_sizes, int n_in,
                              void* d_out, int out_size, void* d_ws, size_t ws_size,
                              hipStream_t stream) {
  nerf_kernel<<<NRAYS / 4, 256, 0, stream>>>(
      (fpp)d_in[0], (fpp)d_in[1], (fpp)d_in[2],
      (fpp)d_in[3], (fpp)d_in[4], (fpp)d_in[5], (fpp)d_in[6],
      (fpp)d_in[7], (fpp)d_in[8], (fpp)d_in[9], (fpp)d_in[10],
      (fpp)d_in[11], (fpp)d_in[12], (fpp)d_in[13], (fpp)d_in[14],
      (float*)d_out);
}

// Round 4
// 296.481 us; speedup vs baseline: 1.1009x; 1.1009x over previous
//
#include <hip/hip_runtime.h>

#define NRAYS 8192
typedef const float* fpp;

typedef short bf16x8 __attribute__((ext_vector_type(8)));
typedef short sh4    __attribute__((ext_vector_type(4)));
typedef float f32x4  __attribute__((ext_vector_type(4)));

__device__ __forceinline__ short f2bf(float f) {           // RNE fp32->bf16
  unsigned u = __float_as_uint(f);
  return (short)((u + 0x7FFFu + ((u >> 16) & 1u)) >> 16);
}
__device__ __forceinline__ float bf2f(short s) {
  return __uint_as_float(((unsigned)(unsigned short)s) << 16);
}
__device__ __forceinline__ f32x4 MFMA(bf16x8 a, bf16x8 b, f32x4 c) {
  return __builtin_amdgcn_mfma_f32_16x16x32_bf16(a, b, c, 0, 0, 0);
}
__device__ __forceinline__ float waveAllSum(float v) {
#pragma unroll
  for (int off = 32; off > 0; off >>= 1) v += __shfl_xor(v, off, 64);
  return v;
}

// output layout (flat fp32): image[8192,3]@0 depth@24576 dvar@32768 coord@40960
// rgbs[8192,256,3]@65536 clip[8192,32]@6356992
#define OFF_IMG   0
#define OFF_DEPTH 24576
#define OFF_VAR   32768
#define OFF_COORD 40960
#define OFF_RGBS  65536
#define OFF_CLIP  6356992

// geo row layout (bf16): col0 = sigma, col f(1..15) = geo[f-1]; stride 24 shorts (48B)
#define GSTR 24

__global__ __launch_bounds__(256) void nerf_kernel(
    fpp rays_o, fpp rays_d, fpp dnorms,
    fpp Wd1, fpp bd1, fpp Wd2, fpp bd2,
    fpp Wc1, fpp bc1, fpp Wc2, fpp bc2,
    fpp Wk1, fpp bk1, fpp Wk2, fpp bk2,
    float* out)
{
  __shared__ float4 wd1s[64];          // {Wd1[0][h],Wd1[1][h],Wd1[2][h],bd1[h]}
  __shared__ float4 wc2s[64];          // {Wc2[h][0..2],0}
  __shared__ short  geos[4][256 * GSTR];
  __shared__ float  sigs[4][256];
  __shared__ float  wbuf[4][256];

  const int tid = threadIdx.x;
  if (tid < 64) {
    wd1s[tid] = make_float4(Wd1[tid], Wd1[64 + tid], Wd1[128 + tid], bd1[tid]);
    wc2s[tid] = make_float4(Wc2[tid * 3], Wc2[tid * 3 + 1], Wc2[tid * 3 + 2], 0.f);
  }
  __syncthreads();

  const int wave = tid >> 6, lane = tid & 63;
  const int c16 = lane & 15, o = lane >> 4;     // frag col / octet(quad)
  const int ray = blockIdx.x * 4 + wave;
  short* geo = &geos[wave][0];
  float* sig = &sigs[wave][0];
  float* wmb = &wbuf[wave][0];

  // ---------------- static weight fragments (per-lane, global reads) ----------
  // A2: D = Wd2^T @ H1^T.  K interleaved: k=2*col+p (p=0 hi,1 lo of H1).
  bf16x8 a2h[4], a2l[4];
#pragma unroll
  for (int kt = 0; kt < 4; kt++) {
#pragma unroll
    for (int j = 0; j < 8; j++) {
      int col = 16 * kt + 4 * o + (j >> 1);
      float wv = Wd2[col * 16 + c16];
      short hi = f2bf(wv);
      a2h[kt][j] = hi;
      a2l[kt][j] = (j & 1) ? (short)0 : f2bf(wv - bf2f(hi));
    }
  }
  // B1a: A[m=h][k = geo-buf col perm]: k0->0(sigma unused), k1..15->Wc1[k+2][h], k16..18->Wc1[k-16][h]
  bf16x8 c1a[4], k1a[4];
#pragma unroll
  for (int ht = 0; ht < 4; ht++) {
#pragma unroll
    for (int j = 0; j < 8; j++) {
      int h = 16 * ht + c16, k = 8 * o + j;
      float wc = 0.f, wk = 0.f;
      if (k >= 1 && k <= 15) wc = Wc1[(k + 2) * 64 + h];
      else if (k >= 16 && k <= 18) wc = Wc1[(k - 16) * 64 + h];
      if (k == 0) wk = Wk1[15 * 64 + h];
      else if (k <= 15) wk = Wk1[(k - 1) * 64 + h];
      c1a[ht][j] = f2bf(wc);
      k1a[ht][j] = f2bf(wk);
    }
  }
  float bd2v[4], bc1v[4][4], bk1v[4][4];
#pragma unroll
  for (int r = 0; r < 4; r++) bd2v[r] = bd2[4 * o + r];
#pragma unroll
  for (int ht = 0; ht < 4; ht++)
#pragma unroll
    for (int r = 0; r < 4; r++) {
      bc1v[ht][r] = bc1[16 * ht + 4 * o + r];
      bk1v[ht][r] = bk1[16 * ht + 4 * o + r];
    }

  // ---------------- ray setup ----------------
  const float ox = rays_o[ray * 3 + 0], oy = rays_o[ray * 3 + 1], oz = rays_o[ray * 3 + 2];
  const float dx = rays_d[ray * 3 + 0], dy = rays_d[ray * 3 + 1], dz = rays_d[ray * 3 + 2];
  const float dn = dnorms[ray];
  const float ixr = 1.f / dx, iyr = 1.f / dy, izr = 1.f / dz;
  float t1x = (-1.f - ox) * ixr, t2x = (1.f - ox) * ixr;
  float t1y = (-1.f - oy) * iyr, t2y = (1.f - oy) * iyr;
  float t1z = (-1.f - oz) * izr, t2z = (1.f - oz) * izr;
  float nearv = fmaxf(fmaxf(fminf(t1x, t2x), fminf(t1y, t2y)), fminf(t1z, t2z));
  nearv = fmaxf(nearv, 0.2f);
  float farv = fminf(fminf(fmaxf(t1x, t2x), fmaxf(t1y, t2y)), fmaxf(t1z, t2z));
  farv = fmaxf(farv, nearv + 0.0001f);
  const float span = farv - nearv;

  // dirs fragment for B1a (covers K rows 16..18)
  bf16x8 dfr;
#pragma unroll
  for (int j = 0; j < 8; j++)
    dfr[j] = (o == 2 && j < 3) ? f2bf(j == 0 ? dx : (j == 1 ? dy : dz)) : (short)0;
  const bf16x8 zf = {0, 0, 0, 0, 0, 0, 0, 0};

  // ================ PHASE 1: density MLP (A1 fp32 VALU + A2 MFMA hi/lo) ======
#pragma unroll 1
  for (int mt = 0; mt < 16; mt++) {
    const int s = mt * 16 + c16;                 // this lane's sample column
    float zt = nearv + span * ((float)s * (1.f / 255.f));
    float xs = fminf(fmaxf(fmaf(dx, zt, ox), -1.f), 1.f);
    float ys = fminf(fmaxf(fmaf(dy, zt, oy), -1.f), 1.f);
    float zs = fminf(fmaxf(fmaf(dz, zt, oz), -1.f), 1.f);
    bf16x8 h1f[4];
#pragma unroll
    for (int kt = 0; kt < 4; kt++) {
#pragma unroll
      for (int i = 0; i < 4; i++) {
        float4 wv = wd1s[16 * kt + 4 * o + i];
        float h = fmaf(xs, wv.x, fmaf(ys, wv.y, fmaf(zs, wv.z, wv.w)));
        h = fmaxf(h, 0.f);
        short hi = f2bf(h);
        h1f[kt][2 * i]     = hi;
        h1f[kt][2 * i + 1] = f2bf(h - bf2f(hi));
      }
    }
    f32x4 acc = {bd2v[0], bd2v[1], bd2v[2], bd2v[3]};
#pragma unroll
    for (int kt = 0; kt < 4; kt++) acc = MFMA(a2h[kt], h1f[kt], acc);
#pragma unroll
    for (int kt = 0; kt < 4; kt++) acc = MFMA(a2l[kt], h1f[kt], acc);
    // D[f=4o+r][sample s]; f==0 is sigma-logit
    float sgm = expf(acc[0]);                    // meaningful on o==0 lanes
    sh4 pk;
    pk[0] = (o == 0) ? f2bf(sgm) : f2bf(acc[0]);
    pk[1] = f2bf(acc[1]); pk[2] = f2bf(acc[2]); pk[3] = f2bf(acc[3]);
    *(sh4*)&geo[s * GSTR + 4 * o] = pk;
    if (o == 0) sig[s] = sgm;
  }

  // ================ transmittance scan (t-layout, fp32, proven) ==============
  float z[4], wm[4];
  float ws, swz, depth, var, cx, cy, cz;
  {
    f32x4 sgv = *(f32x4*)&sig[lane * 4];
    float alpha[4], w[4], v[4], m[4];
#pragma unroll
    for (int i = 0; i < 4; i++) {
      int t = lane * 4 + i;
      z[i] = nearv + span * ((float)t * (1.f / 255.f));
      float delta = (t < 255) ? span * (1.f / 255.f) : span * (1.f / 256.f);
      alpha[i] = 1.f - expf(-delta * sgv[i]);
      v[i] = 1.f - alpha[i] + 1e-15f;
    }
    m[0] = 1.f; m[1] = v[0]; m[2] = m[1] * v[1]; m[3] = m[2] * v[2];
    float ip = m[3] * v[3];
#pragma unroll
    for (int off = 1; off < 64; off <<= 1) {
      float u = __shfl_up(ip, off, 64);
      if (lane >= off) ip *= u;
    }
    float E = __shfl_up(ip, 1, 64);
    if (lane == 0) E = 1.f;
    ws = 0.f; swz = 0.f; cx = 0.f; cy = 0.f; cz = 0.f;
#pragma unroll
    for (int i = 0; i < 4; i++) {
      w[i] = alpha[i] * (E * m[i]);
      wm[i] = (w[i] > 0.0001f) ? w[i] : 0.f;
      ws += wm[i];
      swz = fmaf(wm[i], z[i], swz);
      float xc = fminf(fmaxf(fmaf(dx, z[i], ox), -1.f), 1.f);
      float yc = fminf(fmaxf(fmaf(dy, z[i], oy), -1.f), 1.f);
      float zc = fminf(fmaxf(fmaf(dz, z[i], oz), -1.f), 1.f);
      cx = fmaf(wm[i], xc, cx); cy = fmaf(wm[i], yc, cy); cz = fmaf(wm[i], zc, cz);
    }
    f32x4 wv4 = {wm[0], wm[1], wm[2], wm[3]};
    *(f32x4*)&wmb[lane * 4] = wv4;
    ws = waveAllSum(ws); swz = waveAllSum(swz);
    cx = waveAllSum(cx); cy = waveAllSum(cy); cz = waveAllSum(cz);
    depth = swz / dn;
    var = 0.f;
#pragma unroll
    for (int i = 0; i < 4; i++) {
      float dd = depth - z[i] / dn;
      var = fmaf(wm[i], dd * dd, var);
    }
    var = waveAllSum(var);
  }
  if (lane == 0) {
    out[OFF_DEPTH + ray] = depth;
    out[OFF_VAR + ray]   = var;
    out[OFF_COORD + ray * 3 + 0] = cx;
    out[OFF_COORD + ray * 3 + 1] = cy;
    out[OFF_COORD + ray * 3 + 2] = cz;
  }

  // ================ PHASE 2: color + clip MLPs via MFMA ======================
  float imgp = 0.f;
  float gp[4][4];
#pragma unroll
  for (int ht = 0; ht < 4; ht++)
#pragma unroll
    for (int r = 0; r < 4; r++) gp[ht][r] = 0.f;

#pragma unroll 1
  for (int mt = 0; mt < 16; mt++) {
    const int s = mt * 16 + c16;
    bf16x8 gfr = zf;
    if (o < 2) gfr = *(bf16x8*)&geo[s * GSTR + 8 * o];
    const float wmv = wmb[s];
    // ---- B1a: HC^T = Wc1''^T @ CIN''^T ----
    bf16x8 bfr1 = (o == 2) ? dfr : gfr;
    float r0 = 0.f, r1 = 0.f, r2 = 0.f;
#pragma unroll
    for (int ht = 0; ht < 4; ht++) {
      f32x4 hc = {bc1v[ht][0], bc1v[ht][1], bc1v[ht][2], bc1v[ht][3]};
      hc = MFMA(c1a[ht], bfr1, hc);
#pragma unroll
      for (int r = 0; r < 4; r++) {
        float hv = fmaxf(hc[r], 0.f);
        float4 w2 = wc2s[16 * ht + 4 * o + r];
        r0 = fmaf(hv, w2.x, r0); r1 = fmaf(hv, w2.y, r1); r2 = fmaf(hv, w2.z, r2);
      }
    }
    // reduce over hidden quads (h spread across o): xor 16, 32
    r0 += __shfl_xor(r0, 16, 64); r0 += __shfl_xor(r0, 32, 64);
    r1 += __shfl_xor(r1, 16, 64); r1 += __shfl_xor(r1, 32, 64);
    r2 += __shfl_xor(r2, 16, 64); r2 += __shfl_xor(r2, 32, 64);
    // ---- B1b epilogue: sigmoid + mask + store + image partial (lane o = channel)
    {
      float rq = (o == 0) ? (r0 + bc2[0]) : ((o == 1) ? (r1 + bc2[1]) : (r2 + bc2[2]));
      float sgd = 1.f / (1.f + __expf(-rq));
      sgd = (wmv > 0.f) ? sgd : 0.f;
      if (o < 3) {
        out[OFF_RGBS + ((long)ray * 256 + s) * 3 + o] = sgd;
        imgp = fmaf(wmv, sgd, imgp);
      }
    }
    // ---- B2a: HK^T = Wk1''^T @ KIN''^T ; weighted hidden accumulation ----
#pragma unroll
    for (int ht = 0; ht < 4; ht++) {
      f32x4 hk = {bk1v[ht][0], bk1v[ht][1], bk1v[ht][2], bk1v[ht][3]};
      hk = MFMA(k1a[ht], gfr, hk);
#pragma unroll
      for (int r = 0; r < 4; r++)
        gp[ht][r] = fmaf(wmv, fmaxf(hk[r], 0.f), gp[ht][r]);
    }
  }

  // image: channel partials live on lanes with o==channel
  float img0 = waveAllSum((o == 0) ? imgp : 0.f);
  float img1 = waveAllSum((o == 1) ? imgp : 0.f);
  float img2 = waveAllSum((o == 2) ? imgp : 0.f);
  if (lane == 0) {
    out[OFF_IMG + ray * 3 + 0] = img0 + (1.f - ws);
    out[OFF_IMG + ray * 3 + 1] = img1 + (1.f - ws);
    out[OFF_IMG + ray * 3 + 2] = img2 + (1.f - ws);
  }

  // ---- B2b: reduce g over samples, then clip = g @ Wk2 + ws*bk2 ----
#pragma unroll
  for (int ht = 0; ht < 4; ht++)
#pragma unroll
    for (int r = 0; r < 4; r++) {
      float g = gp[ht][r];
      g += __shfl_xor(g, 1, 64); g += __shfl_xor(g, 2, 64);
      g += __shfl_xor(g, 4, 64); g += __shfl_xor(g, 8, 64);
      gp[ht][r] = g;                 // g[h], h = 16*ht + 4*o + r (all lanes)
    }
  {
    const int k2 = 2 * c16;
    float cp0 = 0.f, cp1 = 0.f;
#pragma unroll
    for (int ht = 0; ht < 4; ht++)
#pragma unroll
      for (int r = 0; r < 4; r++) {
        int h = 16 * ht + 4 * o + r;
        cp0 = fmaf(gp[ht][r], Wk2[h * 32 + k2], cp0);
        cp1 = fmaf(gp[ht][r], Wk2[h * 32 + k2 + 1], cp1);
      }
    cp0 += __shfl_xor(cp0, 16, 64); cp0 += __shfl_xor(cp0, 32, 64);
    cp1 += __shfl_xor(cp1, 16, 64); cp1 += __shfl_xor(cp1, 32, 64);
    cp0 = fmaf(ws, bk2[k2], cp0);
    cp1 = fmaf(ws, bk2[k2 + 1], cp1);
    if (lane < 16) {
      out[OFF_CLIP + ray * 32 + k2]     = cp0;
      out[OFF_CLIP + ray * 32 + k2 + 1] = cp1;
    }
  }
}

extern "C" void kernel_launch(void* const* d_in, const int* in_sizes, int n_in,
                              void* d_out, int out_size, void* d_ws, size_t ws_size,
                              hipStream_t stream) {
  nerf_kernel<<<NRAYS / 4, 256, 0, stream>>>(
      (fpp)d_in[0], (fpp)d_in[1], (fpp)d_in[2],
      (fpp)d_in[3], (fpp)d_in[4], (fpp)d_in[5], (fpp)d_in[6],
      (fpp)d_in[7], (fpp)d_in[8], (fpp)d_in[9], (fpp)d_in[10],
      (fpp)d_in[11], (fpp)d_in[12], (fpp)d_in[13], (fpp)d_in[14],
      (float*)d_out);
}

// Round 5
// 209.503 us; speedup vs baseline: 1.5579x; 1.4152x over previous
//
#include <hip/hip_runtime.h>

#define NRAYS 8192
typedef const float* fpp;

typedef short bf16x8 __attribute__((ext_vector_type(8)));
typedef short sh4    __attribute__((ext_vector_type(4)));
typedef float f32x4  __attribute__((ext_vector_type(4)));

__device__ __forceinline__ short f2bf(float f) {           // RNE fp32->bf16
  unsigned u = __float_as_uint(f);
  return (short)((u + 0x7FFFu + ((u >> 16) & 1u)) >> 16);
}
__device__ __forceinline__ f32x4 MFMA(bf16x8 a, bf16x8 b, f32x4 c) {
  return __builtin_amdgcn_mfma_f32_16x16x32_bf16(a, b, c, 0, 0, 0);
}
__device__ __forceinline__ float waveAllSum(float v) {
#pragma unroll
  for (int off = 32; off > 0; off >>= 1) v += __shfl_xor(v, off, 64);
  return v;
}

// output layout (flat fp32): image[8192,3]@0 depth@24576 dvar@32768 coord@40960
// rgbs[8192,256,3]@65536 clip[8192,32]@6356992
#define OFF_IMG   0
#define OFF_DEPTH 24576
#define OFF_VAR   32768
#define OFF_COORD 40960
#define OFF_RGBS  65536
#define OFF_CLIP  6356992

__global__ __launch_bounds__(256, 3) void nerf_kernel(
    fpp rays_o, fpp rays_d, fpp dnorms,
    fpp Wd1, fpp bd1, fpp Wd2, fpp bd2,
    fpp Wc1, fpp bc1, fpp Wc2, fpp bc2,
    fpp Wk1, fpp bk1, fpp Wk2, fpp bk2,
    float* out)
{
  // geoA: cols 0-7 (sigma,geo0-6), geoB: cols 8-15 (geo7-14). 16B/sample each:
  // b128 reads/writes are contiguous across lanes -> bank-balanced.
  __shared__ short  geoA[4][256][8];
  __shared__ short  geoB[4][256][8];
  __shared__ float  sigs[4][256];
  __shared__ float  wbuf[4][256];
  __shared__ float4 wc2s[64];          // {Wc2[h][0..2],0}

  const int tid = threadIdx.x;
  if (tid < 64)
    wc2s[tid] = make_float4(Wc2[tid * 3], Wc2[tid * 3 + 1], Wc2[tid * 3 + 2], 0.f);
  __syncthreads();

  const int wave = tid >> 6, lane = tid & 63;
  const int c16 = lane & 15, o = lane >> 4;     // frag col / quad-of-16
  const int ray = blockIdx.x * 4 + wave;
  float* sig = &sigs[wave][0];
  float* wmb = &wbuf[wave][0];

  // ---------------- ray setup ----------------
  const float ox = rays_o[ray * 3 + 0], oy = rays_o[ray * 3 + 1], oz = rays_o[ray * 3 + 2];
  const float dx = rays_d[ray * 3 + 0], dy = rays_d[ray * 3 + 1], dz = rays_d[ray * 3 + 2];
  const float dn = dnorms[ray];
  const float ixr = 1.f / dx, iyr = 1.f / dy, izr = 1.f / dz;
  float t1x = (-1.f - ox) * ixr, t2x = (1.f - ox) * ixr;
  float t1y = (-1.f - oy) * iyr, t2y = (1.f - oy) * iyr;
  float t1z = (-1.f - oz) * izr, t2z = (1.f - oz) * izr;
  float nearv = fmaxf(fmaxf(fminf(t1x, t2x), fminf(t1y, t2y)), fminf(t1z, t2z));
  nearv = fmaxf(nearv, 0.2f);
  float farv = fminf(fminf(fmaxf(t1x, t2x), fmaxf(t1y, t2y)), fmaxf(t1z, t2z));
  farv = fmaxf(farv, nearv + 0.0001f);
  const float span = farv - nearv;

  // ---------------- static fragments / per-lane constants ----------------
  // A2: A[m=f][k=h], h = 32*kt + 8*o + j
  bf16x8 a2[2];
#pragma unroll
  for (int kt = 0; kt < 2; kt++)
#pragma unroll
    for (int j = 0; j < 8; j++)
      a2[kt][j] = f2bf(Wd2[(32 * kt + 8 * o + j) * 16 + c16]);

  // A1 linearized: h1 = relu(p + q*z) for h = 32*kt + 8*o + j (k index of B frag)
  float p1[16], q1[16];
#pragma unroll
  for (int kt = 0; kt < 2; kt++)
#pragma unroll
    for (int j = 0; j < 8; j++) {
      int h = 32 * kt + 8 * o + j;
      float w0 = Wd1[h], w1 = Wd1[64 + h], w2 = Wd1[128 + h];
      p1[8 * kt + j] = fmaf(w0, ox, fmaf(w1, oy, fmaf(w2, oz, bd1[h])));
      q1[8 * kt + j] = fmaf(w0, dx, fmaf(w1, dy, w2 * dz));
    }

  // B1a / B2a A-fragments (weights): k = geo-buffer column permutation
  bf16x8 c1a[4], k1a[4];
#pragma unroll
  for (int ht = 0; ht < 4; ht++)
#pragma unroll
    for (int j = 0; j < 8; j++) {
      int h = 16 * ht + c16, k = 8 * o + j;
      float wc = 0.f, wk = 0.f;
      if (k >= 1 && k <= 15) wc = Wc1[(k + 2) * 64 + h];
      else if (k >= 16 && k <= 18) wc = Wc1[(k - 16) * 64 + h];
      if (k == 0) wk = Wk1[15 * 64 + h];
      else if (k <= 15) wk = Wk1[(k - 1) * 64 + h];
      c1a[ht][j] = f2bf(wc);
      k1a[ht][j] = f2bf(wk);
    }
  float bd2v[4], bc1v[4][4], bk1v[4][4];
#pragma unroll
  for (int r = 0; r < 4; r++) bd2v[r] = bd2[4 * o + r];
#pragma unroll
  for (int ht = 0; ht < 4; ht++)
#pragma unroll
    for (int r = 0; r < 4; r++) {
      bc1v[ht][r] = bc1[16 * ht + 4 * o + r];
      bk1v[ht][r] = bk1[16 * ht + 4 * o + r];
    }

  // dirs fragment for B1a (K rows 16..18 live on o==2)
  bf16x8 dfr;
#pragma unroll
  for (int j = 0; j < 8; j++)
    dfr[j] = (o == 2 && j < 3) ? f2bf(j == 0 ? dx : (j == 1 ? dy : dz)) : (short)0;
  const bf16x8 zf = {0, 0, 0, 0, 0, 0, 0, 0};

  // ================ PHASE 1: density MLP (A1 VALU-linear + A2 MFMA) ==========
#pragma unroll 1
  for (int mt = 0; mt < 16; mt++) {
    const int s = mt * 16 + c16;
    const float zt = nearv + span * ((float)s * (1.f / 255.f));
    bf16x8 h1f[2];
#pragma unroll
    for (int kt = 0; kt < 2; kt++)
#pragma unroll
      for (int j = 0; j < 8; j++)
        h1f[kt][j] = f2bf(fmaxf(fmaf(q1[8 * kt + j], zt, p1[8 * kt + j]), 0.f));
    f32x4 acc = {bd2v[0], bd2v[1], bd2v[2], bd2v[3]};
    acc = MFMA(a2[0], h1f[0], acc);
    acc = MFMA(a2[1], h1f[1], acc);
    // D[f=4o+r][s]; f==0 is sigma-logit
    float sgm = expf(acc[0]);                    // valid on o==0
    sh4 pk;
    pk[0] = (o == 0) ? f2bf(sgm) : f2bf(acc[0]);
    pk[1] = f2bf(acc[1]); pk[2] = f2bf(acc[2]); pk[3] = f2bf(acc[3]);
    if (o < 2) *(sh4*)&geoA[wave][s][4 * o] = pk;
    else       *(sh4*)&geoB[wave][s][4 * (o - 2)] = pk;
    if (o == 0) sig[s] = sgm;
  }

  // ================ transmittance scan (t-layout fp32, proven) ===============
  float z[4], wm[4];
  float ws, swz, depth, var, cx, cy, cz;
  {
    f32x4 sgv = *(f32x4*)&sig[lane * 4];
    float alpha[4], v[4], m[4];
#pragma unroll
    for (int i = 0; i < 4; i++) {
      int t = lane * 4 + i;
      z[i] = nearv + span * ((float)t * (1.f / 255.f));
      float delta = (t < 255) ? span * (1.f / 255.f) : span * (1.f / 256.f);
      alpha[i] = 1.f - expf(-delta * sgv[i]);
      v[i] = 1.f - alpha[i] + 1e-15f;
    }
    m[0] = 1.f; m[1] = v[0]; m[2] = m[1] * v[1]; m[3] = m[2] * v[2];
    float ip = m[3] * v[3];
#pragma unroll
    for (int off = 1; off < 64; off <<= 1) {
      float u = __shfl_up(ip, off, 64);
      if (lane >= off) ip *= u;
    }
    float E = __shfl_up(ip, 1, 64);
    if (lane == 0) E = 1.f;
    ws = 0.f; swz = 0.f; cx = 0.f; cy = 0.f; cz = 0.f;
#pragma unroll
    for (int i = 0; i < 4; i++) {
      float w = alpha[i] * (E * m[i]);
      wm[i] = (w > 0.0001f) ? w : 0.f;
      ws += wm[i];
      swz = fmaf(wm[i], z[i], swz);
      float xc = fminf(fmaxf(fmaf(dx, z[i], ox), -1.f), 1.f);
      float yc = fminf(fmaxf(fmaf(dy, z[i], oy), -1.f), 1.f);
      float zc = fminf(fmaxf(fmaf(dz, z[i], oz), -1.f), 1.f);
      cx = fmaf(wm[i], xc, cx); cy = fmaf(wm[i], yc, cy); cz = fmaf(wm[i], zc, cz);
    }
    f32x4 wv4 = {wm[0], wm[1], wm[2], wm[3]};
    *(f32x4*)&wmb[lane * 4] = wv4;
    ws = waveAllSum(ws); swz = waveAllSum(swz);
    cx = waveAllSum(cx); cy = waveAllSum(cy); cz = waveAllSum(cz);
    depth = swz / dn;
    var = 0.f;
#pragma unroll
    for (int i = 0; i < 4; i++) {
      float dd = depth - z[i] / dn;
      var = fmaf(wm[i], dd * dd, var);
    }
    var = waveAllSum(var);
  }
  if (lane == 0) {
    out[OFF_DEPTH + ray] = depth;
    out[OFF_VAR + ray]   = var;
    out[OFF_COORD + ray * 3 + 0] = cx;
    out[OFF_COORD + ray * 3 + 1] = cy;
    out[OFF_COORD + ray * 3 + 2] = cz;
  }

  // ================ PHASE 2: color + clip MLPs via MFMA ======================
  float imgp = 0.f;
  float gp[4][4];
#pragma unroll
  for (int ht = 0; ht < 4; ht++)
#pragma unroll
    for (int r = 0; r < 4; r++) gp[ht][r] = 0.f;

#pragma unroll 1
  for (int mt = 0; mt < 16; mt++) {
    const int s = mt * 16 + c16;
    bf16x8 gfr = zf;
    if (o == 0)      gfr = *(bf16x8*)&geoA[wave][s][0];
    else if (o == 1) gfr = *(bf16x8*)&geoB[wave][s][0];
    const float wmv = wmb[s];
    // ---- B1a ----
    bf16x8 bfr1 = (o == 2) ? dfr : gfr;
    float r0 = 0.f, r1 = 0.f, r2 = 0.f;
#pragma unroll
    for (int ht = 0; ht < 4; ht++) {
      f32x4 hc = {bc1v[ht][0], bc1v[ht][1], bc1v[ht][2], bc1v[ht][3]};
      hc = MFMA(c1a[ht], bfr1, hc);
#pragma unroll
      for (int r = 0; r < 4; r++) {
        float hv = fmaxf(hc[r], 0.f);
        float4 w2 = wc2s[16 * ht + 4 * o + r];
        r0 = fmaf(hv, w2.x, r0); r1 = fmaf(hv, w2.y, r1); r2 = fmaf(hv, w2.z, r2);
      }
    }
    r0 += __shfl_xor(r0, 16, 64); r0 += __shfl_xor(r0, 32, 64);
    r1 += __shfl_xor(r1, 16, 64); r1 += __shfl_xor(r1, 32, 64);
    r2 += __shfl_xor(r2, 16, 64); r2 += __shfl_xor(r2, 32, 64);
    // ---- B1b epilogue: sigmoid + mask + store + image partial ----
    {
      float rq = (o == 0) ? (r0 + bc2[0]) : ((o == 1) ? (r1 + bc2[1]) : (r2 + bc2[2]));
      float sgd = 1.f / (1.f + __expf(-rq));
      sgd = (wmv > 0.f) ? sgd : 0.f;
      if (o < 3) {
        out[OFF_RGBS + ((long)ray * 256 + s) * 3 + o] = sgd;
        imgp = fmaf(wmv, sgd, imgp);
      }
    }
    // ---- B2a: weighted hidden accumulation ----
#pragma unroll
    for (int ht = 0; ht < 4; ht++) {
      f32x4 hk = {bk1v[ht][0], bk1v[ht][1], bk1v[ht][2], bk1v[ht][3]};
      hk = MFMA(k1a[ht], gfr, hk);
#pragma unroll
      for (int r = 0; r < 4; r++)
        gp[ht][r] = fmaf(wmv, fmaxf(hk[r], 0.f), gp[ht][r]);
    }
  }

  float img0 = waveAllSum((o == 0) ? imgp : 0.f);
  float img1 = waveAllSum((o == 1) ? imgp : 0.f);
  float img2 = waveAllSum((o == 2) ? imgp : 0.f);
  if (lane == 0) {
    out[OFF_IMG + ray * 3 + 0] = img0 + (1.f - ws);
    out[OFF_IMG + ray * 3 + 1] = img1 + (1.f - ws);
    out[OFF_IMG + ray * 3 + 2] = img2 + (1.f - ws);
  }

  // ---- B2b: reduce g over samples, then clip = g @ Wk2 + ws*bk2 ----
#pragma unroll
  for (int ht = 0; ht < 4; ht++)
#pragma unroll
    for (int r = 0; r < 4; r++) {
      float g = gp[ht][r];
      g += __shfl_xor(g, 1, 64); g += __shfl_xor(g, 2, 64);
      g += __shfl_xor(g, 4, 64); g += __shfl_xor(g, 8, 64);
      gp[ht][r] = g;                 // g[h], h = 16*ht + 4*o + r
    }
  {
    const int k2 = 2 * c16;
    float cp0 = 0.f, cp1 = 0.f;
#pragma unroll
    for (int ht = 0; ht < 4; ht++)
#pragma unroll
      for (int r = 0; r < 4; r++) {
        int h = 16 * ht + 4 * o + r;
        cp0 = fmaf(gp[ht][r], Wk2[h * 32 + k2], cp0);
        cp1 = fmaf(gp[ht][r], Wk2[h * 32 + k2 + 1], cp1);
      }
    cp0 += __shfl_xor(cp0, 16, 64); cp0 += __shfl_xor(cp0, 32, 64);
    cp1 += __shfl_xor(cp1, 16, 64); cp1 += __shfl_xor(cp1, 32, 64);
    cp0 = fmaf(ws, bk2[k2], cp0);
    cp1 = fmaf(ws, bk2[k2 + 1], cp1);
    if (lane < 16) {
      out[OFF_CLIP + ray * 32 + k2]     = cp0;
      out[OFF_CLIP + ray * 32 + k2 + 1] = cp1;
    }
  }
}

extern "C" void kernel_launch(void* const* d_in, const int* in_sizes, int n_in,
                              void* d_out, int out_size, void* d_ws, size_t ws_size,
                              hipStream_t stream) {
  nerf_kernel<<<NRAYS / 4, 256, 0, stream>>>(
      (fpp)d_in[0], (fpp)d_in[1], (fpp)d_in[2],
      (fpp)d_in[3], (fpp)d_in[4], (fpp)d_in[5], (fpp)d_in[6],
      (fpp)d_in[7], (fpp)d_in[8], (fpp)d_in[9], (fpp)d_in[10],
      (fpp)d_in[11], (fpp)d_in[12], (fpp)d_in[13], (fpp)d_in[14],
      (float*)d_out);
}

// Round 6
// 197.563 us; speedup vs baseline: 1.6521x; 1.0604x over previous
//
#include <hip/hip_runtime.h>

#define NRAYS 8192
typedef const float* fpp;

typedef short bf16x8 __attribute__((ext_vector_type(8)));
typedef short sh4    __attribute__((ext_vector_type(4)));
typedef float f32x4  __attribute__((ext_vector_type(4)));

__device__ __forceinline__ short f2bf(float f) {           // RNE fp32->bf16
  unsigned u = __float_as_uint(f);
  return (short)((u + 0x7FFFu + ((u >> 16) & 1u)) >> 16);
}
__device__ __forceinline__ f32x4 MFMA(bf16x8 a, bf16x8 b, f32x4 c) {
  return __builtin_amdgcn_mfma_f32_16x16x32_bf16(a, b, c, 0, 0, 0);
}
__device__ __forceinline__ float waveAllSum(float v) {
#pragma unroll
  for (int off = 32; off > 0; off >>= 1) v += __shfl_xor(v, off, 64);
  return v;
}

// output layout (flat fp32): image[8192,3]@0 depth@24576 dvar@32768 coord@40960
// rgbs[8192,256,3]@65536 clip[8192,32]@6356992
#define OFF_IMG   0
#define OFF_DEPTH 24576
#define OFF_VAR   32768
#define OFF_COORD 40960
#define OFF_RGBS  65536
#define OFF_CLIP  6356992

__global__ __launch_bounds__(256) void nerf_kernel(
    fpp rays_o, fpp rays_d, fpp dnorms,
    fpp Wd1, fpp bd1, fpp Wd2, fpp bd2,
    fpp Wc1, fpp bc1, fpp Wc2, fpp bc2,
    fpp Wk1, fpp bk1, fpp Wk2, fpp bk2,
    float* out)
{
  // geoA: cols 0-7 (sigma,geo0-6), geoB: cols 8-15 (geo7-14). 16B/sample each.
  __shared__ short  geoA[4][256][8];
  __shared__ short  geoB[4][256][8];
  __shared__ float  sigs[4][256];
  __shared__ float  wbuf[4][256];
  __shared__ float4 wc2s[64];          // {Wc2[h][0..2],0}
  __shared__ __align__(16) float sBd2[16];
  __shared__ __align__(16) float sBc1[64];
  __shared__ __align__(16) float sBk1[64];

  const int tid = threadIdx.x;
  if (tid < 64) {
    wc2s[tid] = make_float4(Wc2[tid * 3], Wc2[tid * 3 + 1], Wc2[tid * 3 + 2], 0.f);
    sBc1[tid] = bc1[tid];
    sBk1[tid] = bk1[tid];
    if (tid < 16) sBd2[tid] = bd2[tid];
  }
  __syncthreads();

  const int wave = tid >> 6, lane = tid & 63;
  const int c16 = lane & 15, o = lane >> 4;     // frag col / quad-of-16
  const int ray = blockIdx.x * 4 + wave;
  float* sig = &sigs[wave][0];
  float* wmb = &wbuf[wave][0];

  // ---------------- ray setup ----------------
  const float ox = rays_o[ray * 3 + 0], oy = rays_o[ray * 3 + 1], oz = rays_o[ray * 3 + 2];
  const float dx = rays_d[ray * 3 + 0], dy = rays_d[ray * 3 + 1], dz = rays_d[ray * 3 + 2];
  const float dn = dnorms[ray];
  const float ixr = 1.f / dx, iyr = 1.f / dy, izr = 1.f / dz;
  float t1x = (-1.f - ox) * ixr, t2x = (1.f - ox) * ixr;
  float t1y = (-1.f - oy) * iyr, t2y = (1.f - oy) * iyr;
  float t1z = (-1.f - oz) * izr, t2z = (1.f - oz) * izr;
  float nearv = fmaxf(fmaxf(fminf(t1x, t2x), fminf(t1y, t2y)), fminf(t1z, t2z));
  nearv = fmaxf(nearv, 0.2f);
  float farv = fminf(fminf(fmaxf(t1x, t2x), fmaxf(t1y, t2y)), fmaxf(t1z, t2z));
  farv = fmaxf(farv, nearv + 0.0001f);
  const float span = farv - nearv;

  // ---------------- static fragments / per-lane constants ----------------
  // A2: A[m=f][k=h], h = 32*kt + 8*o + j
  bf16x8 a2[2];
#pragma unroll
  for (int kt = 0; kt < 2; kt++)
#pragma unroll
    for (int j = 0; j < 8; j++)
      a2[kt][j] = f2bf(Wd2[(32 * kt + 8 * o + j) * 16 + c16]);

  // A1 linearized: h1 = relu(p + q*z) for h = 32*kt + 8*o + j (k index of B frag)
  float p1[16], q1[16];
#pragma unroll
  for (int kt = 0; kt < 2; kt++)
#pragma unroll
    for (int j = 0; j < 8; j++) {
      int h = 32 * kt + 8 * o + j;
      float w0 = Wd1[h], w1 = Wd1[64 + h], w2 = Wd1[128 + h];
      p1[8 * kt + j] = fmaf(w0, ox, fmaf(w1, oy, fmaf(w2, oz, bd1[h])));
      q1[8 * kt + j] = fmaf(w0, dx, fmaf(w1, dy, w2 * dz));
    }

  // B1a / B2a A-fragments (weights): k = geo-buffer column permutation
  bf16x8 c1a[4], k1a[4];
#pragma unroll
  for (int ht = 0; ht < 4; ht++)
#pragma unroll
    for (int j = 0; j < 8; j++) {
      int h = 16 * ht + c16, k = 8 * o + j;
      float wc = 0.f, wk = 0.f;
      if (k >= 1 && k <= 15) wc = Wc1[(k + 2) * 64 + h];
      else if (k >= 16 && k <= 18) wc = Wc1[(k - 16) * 64 + h];
      if (k == 0) wk = Wk1[15 * 64 + h];
      else if (k <= 15) wk = Wk1[(k - 1) * 64 + h];
      c1a[ht][j] = f2bf(wc);
      k1a[ht][j] = f2bf(wk);
    }

  // dirs fragment for B1a (K rows 16..18 live on o==2)
  bf16x8 dfr;
#pragma unroll
  for (int j = 0; j < 8; j++)
    dfr[j] = (o == 2 && j < 3) ? f2bf(j == 0 ? dx : (j == 1 ? dy : dz)) : (short)0;
  const bf16x8 zf = {0, 0, 0, 0, 0, 0, 0, 0};

  // ================ PHASE 1: density MLP (A1 VALU-linear + A2 MFMA) ==========
#pragma unroll 1
  for (int mt = 0; mt < 16; mt++) {
    const int s = mt * 16 + c16;
    const float zt = nearv + span * ((float)s * (1.f / 255.f));
    bf16x8 h1f[2];
#pragma unroll
    for (int kt = 0; kt < 2; kt++)
#pragma unroll
      for (int j = 0; j < 8; j++)
        h1f[kt][j] = f2bf(fmaxf(fmaf(q1[8 * kt + j], zt, p1[8 * kt + j]), 0.f));
    f32x4 acc = *(f32x4*)&sBd2[4 * o];
    acc = MFMA(a2[0], h1f[0], acc);
    acc = MFMA(a2[1], h1f[1], acc);
    // D[f=4o+r][s]; f==0 is sigma-logit
    float sgm = expf(acc[0]);                    // valid on o==0
    sh4 pk;
    pk[0] = (o == 0) ? f2bf(sgm) : f2bf(acc[0]);
    pk[1] = f2bf(acc[1]); pk[2] = f2bf(acc[2]); pk[3] = f2bf(acc[3]);
    if (o < 2) *(sh4*)&geoA[wave][s][4 * o] = pk;
    else       *(sh4*)&geoB[wave][s][4 * (o - 2)] = pk;
    if (o == 0) sig[s] = sgm;
  }

  // ================ transmittance scan (t-layout fp32, proven) ===============
  float z[4], wm[4];
  float ws, swz, depth, var, cx, cy, cz;
  {
    f32x4 sgv = *(f32x4*)&sig[lane * 4];
    float alpha[4], v[4], m[4];
#pragma unroll
    for (int i = 0; i < 4; i++) {
      int t = lane * 4 + i;
      z[i] = nearv + span * ((float)t * (1.f / 255.f));
      float delta = (t < 255) ? span * (1.f / 255.f) : span * (1.f / 256.f);
      alpha[i] = 1.f - expf(-delta * sgv[i]);
      v[i] = 1.f - alpha[i] + 1e-15f;
    }
    m[0] = 1.f; m[1] = v[0]; m[2] = m[1] * v[1]; m[3] = m[2] * v[2];
    float ip = m[3] * v[3];
#pragma unroll
    for (int off = 1; off < 64; off <<= 1) {
      float u = __shfl_up(ip, off, 64);
      if (lane >= off) ip *= u;
    }
    float E = __shfl_up(ip, 1, 64);
    if (lane == 0) E = 1.f;
    ws = 0.f; swz = 0.f; cx = 0.f; cy = 0.f; cz = 0.f;
#pragma unroll
    for (int i = 0; i < 4; i++) {
      float w = alpha[i] * (E * m[i]);
      wm[i] = (w > 0.0001f) ? w : 0.f;
      ws += wm[i];
      swz = fmaf(wm[i], z[i], swz);
      float xc = fminf(fmaxf(fmaf(dx, z[i], ox), -1.f), 1.f);
      float yc = fminf(fmaxf(fmaf(dy, z[i], oy), -1.f), 1.f);
      float zc = fminf(fmaxf(fmaf(dz, z[i], oz), -1.f), 1.f);
      cx = fmaf(wm[i], xc, cx); cy = fmaf(wm[i], yc, cy); cz = fmaf(wm[i], zc, cz);
    }
    f32x4 wv4 = {wm[0], wm[1], wm[2], wm[3]};
    *(f32x4*)&wmb[lane * 4] = wv4;
    ws = waveAllSum(ws); swz = waveAllSum(swz);
    cx = waveAllSum(cx); cy = waveAllSum(cy); cz = waveAllSum(cz);
    depth = swz / dn;
    var = 0.f;
#pragma unroll
    for (int i = 0; i < 4; i++) {
      float dd = depth - z[i] / dn;
      var = fmaf(wm[i], dd * dd, var);
    }
    var = waveAllSum(var);
  }
  if (lane == 0) {
    out[OFF_DEPTH + ray] = depth;
    out[OFF_VAR + ray]   = var;
    out[OFF_COORD + ray * 3 + 0] = cx;
    out[OFF_COORD + ray * 3 + 1] = cy;
    out[OFF_COORD + ray * 3 + 2] = cz;
  }

  // ================ PHASE 2: color + clip MLPs via MFMA ======================
  float imgp = 0.f;
  float gp[4][4];
#pragma unroll
  for (int ht = 0; ht < 4; ht++)
#pragma unroll
    for (int r = 0; r < 4; r++) gp[ht][r] = 0.f;

#pragma unroll 1
  for (int mt = 0; mt < 16; mt++) {
    const int s = mt * 16 + c16;
    bf16x8 gfr = zf;
    if (o == 0)      gfr = *(bf16x8*)&geoA[wave][s][0];
    else if (o == 1) gfr = *(bf16x8*)&geoB[wave][s][0];
    const float wmv = wmb[s];
    // ---- B1a ----
    bf16x8 bfr1 = (o == 2) ? dfr : gfr;
    float r0 = 0.f, r1 = 0.f, r2 = 0.f;
#pragma unroll
    for (int ht = 0; ht < 4; ht++) {
      f32x4 hc = MFMA(c1a[ht], bfr1, *(f32x4*)&sBc1[16 * ht + 4 * o]);
#pragma unroll
      for (int r = 0; r < 4; r++) {
        float hv = fmaxf(hc[r], 0.f);
        float4 w2 = wc2s[16 * ht + 4 * o + r];
        r0 = fmaf(hv, w2.x, r0); r1 = fmaf(hv, w2.y, r1); r2 = fmaf(hv, w2.z, r2);
      }
    }
    r0 += __shfl_xor(r0, 16, 64); r0 += __shfl_xor(r0, 32, 64);
    r1 += __shfl_xor(r1, 16, 64); r1 += __shfl_xor(r1, 32, 64);
    r2 += __shfl_xor(r2, 16, 64); r2 += __shfl_xor(r2, 32, 64);
    // ---- B1b epilogue: sigmoid + mask + store + image partial ----
    {
      float rq = (o == 0) ? (r0 + bc2[0]) : ((o == 1) ? (r1 + bc2[1]) : (r2 + bc2[2]));
      float sgd = 1.f / (1.f + __expf(-rq));
      sgd = (wmv > 0.f) ? sgd : 0.f;
      if (o < 3) {
        out[OFF_RGBS + ((long)ray * 256 + s) * 3 + o] = sgd;
        imgp = fmaf(wmv, sgd, imgp);
      }
    }
    // ---- B2a: weighted hidden accumulation ----
#pragma unroll
    for (int ht = 0; ht < 4; ht++) {
      f32x4 hk = MFMA(k1a[ht], gfr, *(f32x4*)&sBk1[16 * ht + 4 * o]);
#pragma unroll
      for (int r = 0; r < 4; r++)
        gp[ht][r] = fmaf(wmv, fmaxf(hk[r], 0.f), gp[ht][r]);
    }
  }

  float img0 = waveAllSum((o == 0) ? imgp : 0.f);
  float img1 = waveAllSum((o == 1) ? imgp : 0.f);
  float img2 = waveAllSum((o == 2) ? imgp : 0.f);
  if (lane == 0) {
    out[OFF_IMG + ray * 3 + 0] = img0 + (1.f - ws);
    out[OFF_IMG + ray * 3 + 1] = img1 + (1.f - ws);
    out[OFF_IMG + ray * 3 + 2] = img2 + (1.f - ws);
  }

  // ---- B2b: reduce g over samples, then clip = g @ Wk2 + ws*bk2 ----
#pragma unroll
  for (int ht = 0; ht < 4; ht++)
#pragma unroll
    for (int r = 0; r < 4; r++) {
      float g = gp[ht][r];
      g += __shfl_xor(g, 1, 64); g += __shfl_xor(g, 2, 64);
      g += __shfl_xor(g, 4, 64); g += __shfl_xor(g, 8, 64);
      gp[ht][r] = g;                 // g[h], h = 16*ht + 4*o + r
    }
  {
    const int k2 = 2 * c16;
    float cp0 = 0.f, cp1 = 0.f;
#pragma unroll
    for (int ht = 0; ht < 4; ht++)
#pragma unroll
      for (int r = 0; r < 4; r++) {
        int h = 16 * ht + 4 * o + r;
        cp0 = fmaf(gp[ht][r], Wk2[h * 32 + k2], cp0);
        cp1 = fmaf(gp[ht][r], Wk2[h * 32 + k2 + 1], cp1);
      }
    cp0 += __shfl_xor(cp0, 16, 64); cp0 += __shfl_xor(cp0, 32, 64);
    cp1 += __shfl_xor(cp1, 16, 64); cp1 += __shfl_xor(cp1, 32, 64);
    cp0 = fmaf(ws, bk2[k2], cp0);
    cp1 = fmaf(ws, bk2[k2 + 1], cp1);
    if (lane < 16) {
      out[OFF_CLIP + ray * 32 + k2]     = cp0;
      out[OFF_CLIP + ray * 32 + k2 + 1] = cp1;
    }
  }
}

extern "C" void kernel_launch(void* const* d_in, const int* in_sizes, int n_in,
                              void* d_out, int out_size, void* d_ws, size_t ws_size,
                              hipStream_t stream) {
  nerf_kernel<<<NRAYS / 4, 256, 0, stream>>>(
      (fpp)d_in[0], (fpp)d_in[1], (fpp)d_in[2],
      (fpp)d_in[3], (fpp)d_in[4], (fpp)d_in[5], (fpp)d_in[6],
      (fpp)d_in[7], (fpp)d_in[8], (fpp)d_in[9], (fpp)d_in[10],
      (fpp)d_in[11], (fpp)d_in[12], (fpp)d_in[13], (fpp)d_in[14],
      (float*)d_out);
}

// Round 7
// 187.780 us; speedup vs baseline: 1.7382x; 1.0521x over previous
//
#include <hip/hip_runtime.h>

#define NRAYS 8192
typedef const float* fpp;
typedef unsigned int uint;

typedef short bf16x8 __attribute__((ext_vector_type(8)));
typedef int   i32x4  __attribute__((ext_vector_type(4)));
typedef int   i32x2  __attribute__((ext_vector_type(2)));
typedef float f32x4  __attribute__((ext_vector_type(4)));

__device__ __forceinline__ short f2bf(float f) {           // RNE fp32->bf16
  unsigned u = __float_as_uint(f);
  return (short)((u + 0x7FFFu + ((u >> 16) & 1u)) >> 16);
}
// pack2: low short = bf16(a), high short = bf16(b); round-to-nearest via +0x8000
__device__ __forceinline__ int pk2(float a, float b) {
  return (int)__builtin_amdgcn_perm(__float_as_uint(b) + 0x8000u,
                                    __float_as_uint(a) + 0x8000u, 0x07060302u);
}
__device__ __forceinline__ f32x4 MFMA(bf16x8 a, bf16x8 b, f32x4 c) {
  return __builtin_amdgcn_mfma_f32_16x16x32_bf16(a, b, c, 0, 0, 0);
}
__device__ __forceinline__ float waveAllSum(float v) {
#pragma unroll
  for (int off = 32; off > 0; off >>= 1) v += __shfl_xor(v, off, 64);
  return v;
}

// output layout (flat fp32): image[8192,3]@0 depth@24576 dvar@32768 coord@40960
// rgbs[8192,256,3]@65536 clip[8192,32]@6356992
#define OFF_IMG   0
#define OFF_DEPTH 24576
#define OFF_VAR   32768
#define OFF_COORD 40960
#define OFF_RGBS  65536
#define OFF_CLIP  6356992

// ---------------- prep kernel: pack weight fragments into d_ws ----------------
// ws layout (uint4): a2[lane*2+kt] @0..127, c1a[lane*4+ht] @128..383, k1a @384..639
__global__ void prep_kernel(fpp Wd2, fpp Wc1, fpp Wk1, uint4* ws) {
  const int lane = threadIdx.x & 63;
  const int c16 = lane & 15, o = lane >> 4;
  uint t[4];
#pragma unroll
  for (int kt = 0; kt < 2; kt++) {
#pragma unroll
    for (int q = 0; q < 4; q++) {
      float w0 = Wd2[(32 * kt + 8 * o + 2 * q) * 16 + c16];
      float w1 = Wd2[(32 * kt + 8 * o + 2 * q + 1) * 16 + c16];
      t[q] = ((uint)(unsigned short)f2bf(w1) << 16) | (uint)(unsigned short)f2bf(w0);
    }
    ws[lane * 2 + kt] = make_uint4(t[0], t[1], t[2], t[3]);
  }
#pragma unroll
  for (int ht = 0; ht < 4; ht++) {
    uint tc[4], tk[4];
#pragma unroll
    for (int q = 0; q < 4; q++) {
      uint pc = 0, pkk = 0;
#pragma unroll
      for (int half = 0; half < 2; half++) {
        int h = 16 * ht + c16, k = 8 * o + 2 * q + half;
        float wc = 0.f, wk = 0.f;
        if (k >= 1 && k <= 15) wc = Wc1[(k + 2) * 64 + h];
        else if (k >= 16 && k <= 18) wc = Wc1[(k - 16) * 64 + h];
        if (k == 0) wk = Wk1[15 * 64 + h];
        else if (k <= 15) wk = Wk1[(k - 1) * 64 + h];
        pc  |= (uint)(unsigned short)f2bf(wc) << (16 * half);
        pkk |= (uint)(unsigned short)f2bf(wk) << (16 * half);
      }
      tc[q] = pc; tk[q] = pkk;
    }
    ws[128 + lane * 4 + ht] = make_uint4(tc[0], tc[1], tc[2], tc[3]);
    ws[384 + lane * 4 + ht] = make_uint4(tk[0], tk[1], tk[2], tk[3]);
  }
}

template <bool PREP>
__global__ __launch_bounds__(256) void nerf_kernel(
    fpp rays_o, fpp rays_d, fpp dnorms,
    fpp Wd1, fpp bd1, fpp Wd2, fpp bd2,
    fpp Wc1, fpp bc1, fpp Wc2, fpp bc2,
    fpp Wk1, fpp bk1, fpp Wk2, fpp bk2,
    const uint4* wsp, float* out)
{
  __shared__ short  geoA[4][256][8];   // cols 0-7 (sigma,geo0-6)
  __shared__ short  geoB[4][256][8];   // cols 8-15 (geo7-14)
  __shared__ float  sigs[4][256];
  __shared__ float  wbuf[4][256];
  __shared__ float4 wc2s[64];          // {Wc2[h][0..2],0}
  __shared__ __align__(16) float sBd2[16];
  __shared__ __align__(16) float sBc1[64];
  __shared__ __align__(16) float sBk1[64];

  const int tid = threadIdx.x;
  if (tid < 64) {
    wc2s[tid] = make_float4(Wc2[tid * 3], Wc2[tid * 3 + 1], Wc2[tid * 3 + 2], 0.f);
    sBc1[tid] = bc1[tid];
    sBk1[tid] = bk1[tid];
    if (tid < 16) sBd2[tid] = bd2[tid];
  }
  __syncthreads();

  const int wave = tid >> 6, lane = tid & 63;
  const int c16 = lane & 15, o = lane >> 4;
  const int ray = blockIdx.x * 4 + wave;
  float* sig = &sigs[wave][0];
  float* wmb = &wbuf[wave][0];

  // ---------------- ray setup ----------------
  const float ox = rays_o[ray * 3 + 0], oy = rays_o[ray * 3 + 1], oz = rays_o[ray * 3 + 2];
  const float dx = rays_d[ray * 3 + 0], dy = rays_d[ray * 3 + 1], dz = rays_d[ray * 3 + 2];
  const float dn = dnorms[ray];
  const float ixr = 1.f / dx, iyr = 1.f / dy, izr = 1.f / dz;
  float t1x = (-1.f - ox) * ixr, t2x = (1.f - ox) * ixr;
  float t1y = (-1.f - oy) * iyr, t2y = (1.f - oy) * iyr;
  float t1z = (-1.f - oz) * izr, t2z = (1.f - oz) * izr;
  float nearv = fmaxf(fmaxf(fminf(t1x, t2x), fminf(t1y, t2y)), fminf(t1z, t2z));
  nearv = fmaxf(nearv, 0.2f);
  float farv = fminf(fminf(fmaxf(t1x, t2x), fmaxf(t1y, t2y)), fmaxf(t1z, t2z));
  farv = fmaxf(farv, nearv + 0.0001f);
  const float span = farv - nearv;

  // ---------------- weight fragments ----------------
  bf16x8 a2[2], c1a[4], k1a[4];
  if (PREP) {
#pragma unroll
    for (int kt = 0; kt < 2; kt++) a2[kt] = __builtin_bit_cast(bf16x8, wsp[lane * 2 + kt]);
#pragma unroll
    for (int ht = 0; ht < 4; ht++) {
      c1a[ht] = __builtin_bit_cast(bf16x8, wsp[128 + lane * 4 + ht]);
      k1a[ht] = __builtin_bit_cast(bf16x8, wsp[384 + lane * 4 + ht]);
    }
  } else {
#pragma unroll
    for (int kt = 0; kt < 2; kt++)
#pragma unroll
      for (int j = 0; j < 8; j++)
        a2[kt][j] = f2bf(Wd2[(32 * kt + 8 * o + j) * 16 + c16]);
#pragma unroll
    for (int ht = 0; ht < 4; ht++)
#pragma unroll
      for (int j = 0; j < 8; j++) {
        int h = 16 * ht + c16, k = 8 * o + j;
        float wc = 0.f, wk = 0.f;
        if (k >= 1 && k <= 15) wc = Wc1[(k + 2) * 64 + h];
        else if (k >= 16 && k <= 18) wc = Wc1[(k - 16) * 64 + h];
        if (k == 0) wk = Wk1[15 * 64 + h];
        else if (k <= 15) wk = Wk1[(k - 1) * 64 + h];
        c1a[ht][j] = f2bf(wc);
        k1a[ht][j] = f2bf(wk);
      }
  }

  // A1 linearized: h1 = relu(p + q*z), h = 32*kt + 8*o + j
  float p1[16], q1[16];
#pragma unroll
  for (int kt = 0; kt < 2; kt++)
#pragma unroll
    for (int j = 0; j < 8; j++) {
      int h = 32 * kt + 8 * o + j;
      float w0 = Wd1[h], w1 = Wd1[64 + h], w2 = Wd1[128 + h];
      p1[8 * kt + j] = fmaf(w0, ox, fmaf(w1, oy, fmaf(w2, oz, bd1[h])));
      q1[8 * kt + j] = fmaf(w0, dx, fmaf(w1, dy, w2 * dz));
    }

  // dirs fragment for B1a (K rows 16..18 live on o==2)
  bf16x8 dfr;
#pragma unroll
  for (int j = 0; j < 8; j++)
    dfr[j] = (o == 2 && j < 3) ? f2bf(j == 0 ? dx : (j == 1 ? dy : dz)) : (short)0;
  const bf16x8 zf = {0, 0, 0, 0, 0, 0, 0, 0};

  // ================ PHASE 1: density MLP (A1 VALU-linear + A2 MFMA) ==========
#pragma unroll 1
  for (int mt = 0; mt < 16; mt++) {
    const int s = mt * 16 + c16;
    const float zt = nearv + span * ((float)s * (1.f / 255.f));
    bf16x8 h1f[2];
#pragma unroll
    for (int kt = 0; kt < 2; kt++) {
      i32x4 tv;
#pragma unroll
      for (int q = 0; q < 4; q++) {
        float a = fmaxf(fmaf(q1[8 * kt + 2 * q],     zt, p1[8 * kt + 2 * q]),     0.f);
        float b = fmaxf(fmaf(q1[8 * kt + 2 * q + 1], zt, p1[8 * kt + 2 * q + 1]), 0.f);
        tv[q] = pk2(a, b);
      }
      h1f[kt] = __builtin_bit_cast(bf16x8, tv);
    }
    f32x4 acc = *(f32x4*)&sBd2[4 * o];
    acc = MFMA(a2[0], h1f[0], acc);
    acc = MFMA(a2[1], h1f[1], acc);
    // D[f=4o+r][s]; f==0 is sigma-logit
    float sgm = __expf(acc[0]);                    // valid on o==0
    i32x2 pkv;
    pkv[0] = pk2((o == 0) ? sgm : acc[0], acc[1]);
    pkv[1] = pk2(acc[2], acc[3]);
    if (o < 2) *(i32x2*)&geoA[wave][s][4 * o] = pkv;
    else       *(i32x2*)&geoB[wave][s][4 * (o - 2)] = pkv;
    if (o == 0) sig[s] = sgm;
  }

  // ================ transmittance scan (t-layout fp32) =======================
  float z[4], wm[4];
  float ws, swz, depth, var, cx, cy, cz;
  {
    f32x4 sgv = *(f32x4*)&sig[lane * 4];
    float alpha[4], v[4], m[4];
#pragma unroll
    for (int i = 0; i < 4; i++) {
      int t = lane * 4 + i;
      z[i] = nearv + span * ((float)t * (1.f / 255.f));
      float delta = (t < 255) ? span * (1.f / 255.f) : span * (1.f / 256.f);
      alpha[i] = 1.f - __expf(-delta * sgv[i]);
      v[i] = 1.f - alpha[i] + 1e-15f;
    }
    m[0] = 1.f; m[1] = v[0]; m[2] = m[1] * v[1]; m[3] = m[2] * v[2];
    float ip = m[3] * v[3];
#pragma unroll
    for (int off = 1; off < 64; off <<= 1) {
      float u = __shfl_up(ip, off, 64);
      if (lane >= off) ip *= u;
    }
    float E = __shfl_up(ip, 1, 64);
    if (lane == 0) E = 1.f;
    ws = 0.f; swz = 0.f; cx = 0.f; cy = 0.f; cz = 0.f;
#pragma unroll
    for (int i = 0; i < 4; i++) {
      float w = alpha[i] * (E * m[i]);
      wm[i] = (w > 0.0001f) ? w : 0.f;
      ws += wm[i];
      swz = fmaf(wm[i], z[i], swz);
      float xc = fminf(fmaxf(fmaf(dx, z[i], ox), -1.f), 1.f);
      float yc = fminf(fmaxf(fmaf(dy, z[i], oy), -1.f), 1.f);
      float zc = fminf(fmaxf(fmaf(dz, z[i], oz), -1.f), 1.f);
      cx = fmaf(wm[i], xc, cx); cy = fmaf(wm[i], yc, cy); cz = fmaf(wm[i], zc, cz);
    }
    f32x4 wv4 = {wm[0], wm[1], wm[2], wm[3]};
    *(f32x4*)&wmb[lane * 4] = wv4;
    ws = waveAllSum(ws); swz = waveAllSum(swz);
    cx = waveAllSum(cx); cy = waveAllSum(cy); cz = waveAllSum(cz);
    depth = swz / dn;
    var = 0.f;
#pragma unroll
    for (int i = 0; i < 4; i++) {
      float dd = depth - z[i] / dn;
      var = fmaf(wm[i], dd * dd, var);
    }
    var = waveAllSum(var);
  }
  if (lane == 0) {
    out[OFF_DEPTH + ray] = depth;
    out[OFF_VAR + ray]   = var;
    out[OFF_COORD + ray * 3 + 0] = cx;
    out[OFF_COORD + ray * 3 + 1] = cy;
    out[OFF_COORD + ray * 3 + 2] = cz;
  }

  // ================ PHASE 2: color + clip MLPs via MFMA ======================
  float imgp = 0.f;
  float gp[4][4];
#pragma unroll
  for (int ht = 0; ht < 4; ht++)
#pragma unroll
    for (int r = 0; r < 4; r++) gp[ht][r] = 0.f;

#pragma unroll 1
  for (int mt = 0; mt < 16; mt++) {
    const int s = mt * 16 + c16;
    bf16x8 gfr = zf;
    if (o == 0)      gfr = *(bf16x8*)&geoA[wave][s][0];
    else if (o == 1) gfr = *(bf16x8*)&geoB[wave][s][0];
    const float wmv = wmb[s];
    // ---- B1a ----
    bf16x8 bfr1 = (o == 2) ? dfr : gfr;
    float r0 = 0.f, r1 = 0.f, r2 = 0.f;
#pragma unroll
    for (int ht = 0; ht < 4; ht++) {
      f32x4 hc = MFMA(c1a[ht], bfr1, *(f32x4*)&sBc1[16 * ht + 4 * o]);
#pragma unroll
      for (int r = 0; r < 4; r++) {
        float hv = fmaxf(hc[r], 0.f);
        float4 w2 = wc2s[16 * ht + 4 * o + r];
        r0 = fmaf(hv, w2.x, r0); r1 = fmaf(hv, w2.y, r1); r2 = fmaf(hv, w2.z, r2);
      }
    }
    r0 += __shfl_xor(r0, 16, 64); r0 += __shfl_xor(r0, 32, 64);
    r1 += __shfl_xor(r1, 16, 64); r1 += __shfl_xor(r1, 32, 64);
    r2 += __shfl_xor(r2, 16, 64); r2 += __shfl_xor(r2, 32, 64);
    // ---- B1b epilogue ----
    {
      float rq = (o == 0) ? (r0 + bc2[0]) : ((o == 1) ? (r1 + bc2[1]) : (r2 + bc2[2]));
      float sgd = __builtin_amdgcn_rcpf(1.f + __expf(-rq));
      sgd = (wmv > 0.f) ? sgd : 0.f;
      if (o < 3) {
        out[OFF_RGBS + ((long)ray * 256 + s) * 3 + o] = sgd;
        imgp = fmaf(wmv, sgd, imgp);
      }
    }
    // ---- B2a ----
#pragma unroll
    for (int ht = 0; ht < 4; ht++) {
      f32x4 hk = MFMA(k1a[ht], gfr, *(f32x4*)&sBk1[16 * ht + 4 * o]);
#pragma unroll
      for (int r = 0; r < 4; r++)
        gp[ht][r] = fmaf(wmv, fmaxf(hk[r], 0.f), gp[ht][r]);
    }
  }

  float img0 = waveAllSum((o == 0) ? imgp : 0.f);
  float img1 = waveAllSum((o == 1) ? imgp : 0.f);
  float img2 = waveAllSum((o == 2) ? imgp : 0.f);
  if (lane == 0) {
    out[OFF_IMG + ray * 3 + 0] = img0 + (1.f - ws);
    out[OFF_IMG + ray * 3 + 1] = img1 + (1.f - ws);
    out[OFF_IMG + ray * 3 + 2] = img2 + (1.f - ws);
  }

  // ---- B2b: reduce g over samples, then clip = g @ Wk2 + ws*bk2 ----
#pragma unroll
  for (int ht = 0; ht < 4; ht++)
#pragma unroll
    for (int r = 0; r < 4; r++) {
      float g = gp[ht][r];
      g += __shfl_xor(g, 1, 64); g += __shfl_xor(g, 2, 64);
      g += __shfl_xor(g, 4, 64); g += __shfl_xor(g, 8, 64);
      gp[ht][r] = g;                 // g[h], h = 16*ht + 4*o + r
    }
  {
    const int k2 = 2 * c16;
    float cp0 = 0.f, cp1 = 0.f;
#pragma unroll
    for (int ht = 0; ht < 4; ht++)
#pragma unroll
      for (int r = 0; r < 4; r++) {
        int h = 16 * ht + 4 * o + r;
        cp0 = fmaf(gp[ht][r], Wk2[h * 32 + k2], cp0);
        cp1 = fmaf(gp[ht][r], Wk2[h * 32 + k2 + 1], cp1);
      }
    cp0 += __shfl_xor(cp0, 16, 64); cp0 += __shfl_xor(cp0, 32, 64);
    cp1 += __shfl_xor(cp1, 16, 64); cp1 += __shfl_xor(cp1, 32, 64);
    cp0 = fmaf(ws, bk2[k2], cp0);
    cp1 = fmaf(ws, bk2[k2 + 1], cp1);
    if (lane < 16) {
      out[OFF_CLIP + ray * 32 + k2]     = cp0;
      out[OFF_CLIP + ray * 32 + k2 + 1] = cp1;
    }
  }
}

extern "C" void kernel_launch(void* const* d_in, const int* in_sizes, int n_in,
                              void* d_out, int out_size, void* d_ws, size_t ws_size,
                              hipStream_t stream) {
  const bool prep = (ws_size >= 10240);
  if (prep) {
    prep_kernel<<<1, 64, 0, stream>>>((fpp)d_in[5], (fpp)d_in[7], (fpp)d_in[11],
                                      (uint4*)d_ws);
    nerf_kernel<true><<<NRAYS / 4, 256, 0, stream>>>(
        (fpp)d_in[0], (fpp)d_in[1], (fpp)d_in[2],
        (fpp)d_in[3], (fpp)d_in[4], (fpp)d_in[5], (fpp)d_in[6],
        (fpp)d_in[7], (fpp)d_in[8], (fpp)d_in[9], (fpp)d_in[10],
        (fpp)d_in[11], (fpp)d_in[12], (fpp)d_in[13], (fpp)d_in[14],
        (const uint4*)d_ws, (float*)d_out);
  } else {
    nerf_kernel<false><<<NRAYS / 4, 256, 0, stream>>>(
        (fpp)d_in[0], (fpp)d_in[1], (fpp)d_in[2],
        (fpp)d_in[3], (fpp)d_in[4], (fpp)d_in[5], (fpp)d_in[6],
        (fpp)d_in[7], (fpp)d_in[8], (fpp)d_in[9], (fpp)d_in[10],
        (fpp)d_in[11], (fpp)d_in[12], (fpp)d_in[13], (fpp)d_in[14],
        (const uint4*)d_ws, (float*)d_out);
  }
}

// Round 8
// 185.665 us; speedup vs baseline: 1.7580x; 1.0114x over previous
//
#include <hip/hip_runtime.h>

#define NRAYS 8192
typedef const float* fpp;
typedef unsigned int uint;

typedef short bf16x8 __attribute__((ext_vector_type(8)));
typedef int   i32x4  __attribute__((ext_vector_type(4)));
typedef int   i32x2  __attribute__((ext_vector_type(2)));
typedef float f32x4  __attribute__((ext_vector_type(4)));

__device__ __forceinline__ short f2bf(float f) {           // RNE fp32->bf16
  unsigned u = __float_as_uint(f);
  return (short)((u + 0x7FFFu + ((u >> 16) & 1u)) >> 16);
}
// pack2: low short = bf16(a), high short = bf16(b); round-to-nearest via +0x8000
__device__ __forceinline__ int pk2(float a, float b) {
  return (int)__builtin_amdgcn_perm(__float_as_uint(b) + 0x8000u,
                                    __float_as_uint(a) + 0x8000u, 0x07060302u);
}
__device__ __forceinline__ f32x4 MFMA(bf16x8 a, bf16x8 b, f32x4 c) {
  return __builtin_amdgcn_mfma_f32_16x16x32_bf16(a, b, c, 0, 0, 0);
}
__device__ __forceinline__ float waveAllSum(float v) {
#pragma unroll
  for (int off = 32; off > 0; off >>= 1) v += __shfl_xor(v, off, 64);
  return v;
}

// output layout (flat fp32): image[8192,3]@0 depth@24576 dvar@32768 coord@40960
// rgbs[8192,256,3]@65536 clip[8192,32]@6356992
#define OFF_IMG   0
#define OFF_DEPTH 24576
#define OFF_VAR   32768
#define OFF_COORD 40960
#define OFF_RGBS  65536
#define OFF_CLIP  6356992

// ---------------- prep kernel: pack weight fragments into d_ws ----------------
// ws layout (uint4): a2[lane*2+kt] @0..127, c1a[lane*4+ht] @128..383, k1a @384..639
__global__ void prep_kernel(fpp Wd2, fpp Wc1, fpp Wk1, uint4* ws) {
  const int lane = threadIdx.x & 63;
  const int c16 = lane & 15, o = lane >> 4;
  uint t[4];
#pragma unroll
  for (int kt = 0; kt < 2; kt++) {
#pragma unroll
    for (int q = 0; q < 4; q++) {
      float w0 = Wd2[(32 * kt + 8 * o + 2 * q) * 16 + c16];
      float w1 = Wd2[(32 * kt + 8 * o + 2 * q + 1) * 16 + c16];
      t[q] = ((uint)(unsigned short)f2bf(w1) << 16) | (uint)(unsigned short)f2bf(w0);
    }
    ws[lane * 2 + kt] = make_uint4(t[0], t[1], t[2], t[3]);
  }
#pragma unroll
  for (int ht = 0; ht < 4; ht++) {
    uint tc[4], tk[4];
#pragma unroll
    for (int q = 0; q < 4; q++) {
      uint pc = 0, pkk = 0;
#pragma unroll
      for (int half = 0; half < 2; half++) {
        int h = 16 * ht + c16, k = 8 * o + 2 * q + half;
        float wc = 0.f, wk = 0.f;
        if (k >= 1 && k <= 15) wc = Wc1[(k + 2) * 64 + h];
        else if (k >= 16 && k <= 18) wc = Wc1[(k - 16) * 64 + h];
        if (k == 0) wk = Wk1[15 * 64 + h];
        else if (k <= 15) wk = Wk1[(k - 1) * 64 + h];
        pc  |= (uint)(unsigned short)f2bf(wc) << (16 * half);
        pkk |= (uint)(unsigned short)f2bf(wk) << (16 * half);
      }
      tc[q] = pc; tk[q] = pkk;
    }
    ws[128 + lane * 4 + ht] = make_uint4(tc[0], tc[1], tc[2], tc[3]);
    ws[384 + lane * 4 + ht] = make_uint4(tk[0], tk[1], tk[2], tk[3]);
  }
}

template <bool PREP>
__global__ __launch_bounds__(256) void nerf_kernel(
    fpp rays_o, fpp rays_d, fpp dnorms,
    fpp Wd1, fpp bd1, fpp Wd2, fpp bd2,
    fpp Wc1, fpp bc1, fpp Wc2, fpp bc2,
    fpp Wk1, fpp bk1, fpp Wk2, fpp bk2,
    const uint4* wsp, float* out)
{
  __shared__ short  geoA[4][256][8];   // cols 0-7 (sigma,geo0-6)
  __shared__ short  geoB[4][256][8];   // cols 8-15 (geo7-14)
  __shared__ float  tmp[4][256];       // phase1: sigma fp32; scan onward: wm
  __shared__ float4 wc2s[64];          // {Wc2[h][0..2],0}
  __shared__ __align__(16) float sBd2[16];
  __shared__ __align__(16) float sBc1[64];
  __shared__ __align__(16) float sBk1[64];

  const int tid = threadIdx.x;
  if (tid < 64) {
    wc2s[tid] = make_float4(Wc2[tid * 3], Wc2[tid * 3 + 1], Wc2[tid * 3 + 2], 0.f);
    sBc1[tid] = bc1[tid];
    sBk1[tid] = bk1[tid];
    if (tid < 16) sBd2[tid] = bd2[tid];
  }
  __syncthreads();

  const int wave = tid >> 6, lane = tid & 63;
  const int c16 = lane & 15, o = lane >> 4;
  const int ray = blockIdx.x * 4 + wave;
  float* swb = &tmp[wave][0];          // sigma, then wm (per-lane same-address reuse)

  // ---------------- ray setup ----------------
  const float ox = rays_o[ray * 3 + 0], oy = rays_o[ray * 3 + 1], oz = rays_o[ray * 3 + 2];
  const float dx = rays_d[ray * 3 + 0], dy = rays_d[ray * 3 + 1], dz = rays_d[ray * 3 + 2];
  const float dn = dnorms[ray];
  const float ixr = 1.f / dx, iyr = 1.f / dy, izr = 1.f / dz;
  float t1x = (-1.f - ox) * ixr, t2x = (1.f - ox) * ixr;
  float t1y = (-1.f - oy) * iyr, t2y = (1.f - oy) * iyr;
  float t1z = (-1.f - oz) * izr, t2z = (1.f - oz) * izr;
  float nearv = fmaxf(fmaxf(fminf(t1x, t2x), fminf(t1y, t2y)), fminf(t1z, t2z));
  nearv = fmaxf(nearv, 0.2f);
  float farv = fminf(fminf(fmaxf(t1x, t2x), fmaxf(t1y, t2y)), fmaxf(t1z, t2z));
  farv = fmaxf(farv, nearv + 0.0001f);
  const float span = farv - nearv;

  // ---------------- weight fragments ----------------
  bf16x8 a2[2], c1a[4], k1a[4];
  if (PREP) {
#pragma unroll
    for (int kt = 0; kt < 2; kt++) a2[kt] = __builtin_bit_cast(bf16x8, wsp[lane * 2 + kt]);
#pragma unroll
    for (int ht = 0; ht < 4; ht++) {
      c1a[ht] = __builtin_bit_cast(bf16x8, wsp[128 + lane * 4 + ht]);
      k1a[ht] = __builtin_bit_cast(bf16x8, wsp[384 + lane * 4 + ht]);
    }
  } else {
#pragma unroll
    for (int kt = 0; kt < 2; kt++)
#pragma unroll
      for (int j = 0; j < 8; j++)
        a2[kt][j] = f2bf(Wd2[(32 * kt + 8 * o + j) * 16 + c16]);
#pragma unroll
    for (int ht = 0; ht < 4; ht++)
#pragma unroll
      for (int j = 0; j < 8; j++) {
        int h = 16 * ht + c16, k = 8 * o + j;
        float wc = 0.f, wk = 0.f;
        if (k >= 1 && k <= 15) wc = Wc1[(k + 2) * 64 + h];
        else if (k >= 16 && k <= 18) wc = Wc1[(k - 16) * 64 + h];
        if (k == 0) wk = Wk1[15 * 64 + h];
        else if (k <= 15) wk = Wk1[(k - 1) * 64 + h];
        c1a[ht][j] = f2bf(wc);
        k1a[ht][j] = f2bf(wk);
      }
  }

  // A1 linearized: h1 = relu(p + q*z), h = 32*kt + 8*o + j
  float p1[16], q1[16];
#pragma unroll
  for (int kt = 0; kt < 2; kt++)
#pragma unroll
    for (int j = 0; j < 8; j++) {
      int h = 32 * kt + 8 * o + j;
      float w0 = Wd1[h], w1 = Wd1[64 + h], w2 = Wd1[128 + h];
      p1[8 * kt + j] = fmaf(w0, ox, fmaf(w1, oy, fmaf(w2, oz, bd1[h])));
      q1[8 * kt + j] = fmaf(w0, dx, fmaf(w1, dy, w2 * dz));
    }

  // dirs fragment for B1a (K rows 16..18 live on o==2)
  bf16x8 dfr;
#pragma unroll
  for (int j = 0; j < 8; j++)
    dfr[j] = (o == 2 && j < 3) ? f2bf(j == 0 ? dx : (j == 1 ? dy : dz)) : (short)0;
  const bf16x8 zf = {0, 0, 0, 0, 0, 0, 0, 0};

  // ================ PHASE 1: density MLP (A1 VALU-linear + A2 MFMA) ==========
#pragma unroll 1
  for (int mt = 0; mt < 16; mt++) {
    const int s = mt * 16 + c16;
    const float zt = nearv + span * ((float)s * (1.f / 255.f));
    bf16x8 h1f[2];
#pragma unroll
    for (int kt = 0; kt < 2; kt++) {
      i32x4 tv;
#pragma unroll
      for (int q = 0; q < 4; q++) {
        float a = fmaxf(fmaf(q1[8 * kt + 2 * q],     zt, p1[8 * kt + 2 * q]),     0.f);
        float b = fmaxf(fmaf(q1[8 * kt + 2 * q + 1], zt, p1[8 * kt + 2 * q + 1]), 0.f);
        tv[q] = pk2(a, b);
      }
      h1f[kt] = __builtin_bit_cast(bf16x8, tv);
    }
    f32x4 acc = *(f32x4*)&sBd2[4 * o];
    acc = MFMA(a2[0], h1f[0], acc);
    acc = MFMA(a2[1], h1f[1], acc);
    // D[f=4o+r][s]; f==0 is sigma-logit
    float sgm = __expf(acc[0]);                    // valid on o==0
    i32x2 pkv;
    pkv[0] = pk2((o == 0) ? sgm : acc[0], acc[1]);
    pkv[1] = pk2(acc[2], acc[3]);
    if (o < 2) *(i32x2*)&geoA[wave][s][4 * o] = pkv;
    else       *(i32x2*)&geoB[wave][s][4 * (o - 2)] = pkv;
    if (o == 0) swb[s] = sgm;
  }

  // ================ transmittance scan (t-layout fp32) =======================
  float z[4], wm[4];
  float ws, swz, depth, var, cx, cy, cz;
  {
    f32x4 sgv = *(f32x4*)&swb[lane * 4];
    float alpha[4], v[4], m[4];
#pragma unroll
    for (int i = 0; i < 4; i++) {
      int t = lane * 4 + i;
      z[i] = nearv + span * ((float)t * (1.f / 255.f));
      float delta = (t < 255) ? span * (1.f / 255.f) : span * (1.f / 256.f);
      alpha[i] = 1.f - __expf(-delta * sgv[i]);
      v[i] = 1.f - alpha[i] + 1e-15f;
    }
    m[0] = 1.f; m[1] = v[0]; m[2] = m[1] * v[1]; m[3] = m[2] * v[2];
    float ip = m[3] * v[3];
#pragma unroll
    for (int off = 1; off < 64; off <<= 1) {
      float u = __shfl_up(ip, off, 64);
      if (lane >= off) ip *= u;
    }
    float E = __shfl_up(ip, 1, 64);
    if (lane == 0) E = 1.f;
    ws = 0.f; swz = 0.f; cx = 0.f; cy = 0.f; cz = 0.f;
#pragma unroll
    for (int i = 0; i < 4; i++) {
      float w = alpha[i] * (E * m[i]);
      wm[i] = (w > 0.0001f) ? w : 0.f;
      ws += wm[i];
      swz = fmaf(wm[i], z[i], swz);
      float xc = fminf(fmaxf(fmaf(dx, z[i], ox), -1.f), 1.f);
      float yc = fminf(fmaxf(fmaf(dy, z[i], oy), -1.f), 1.f);
      float zc = fminf(fmaxf(fmaf(dz, z[i], oz), -1.f), 1.f);
      cx = fmaf(wm[i], xc, cx); cy = fmaf(wm[i], yc, cy); cz = fmaf(wm[i], zc, cz);
    }
    f32x4 wv4 = {wm[0], wm[1], wm[2], wm[3]};
    *(f32x4*)&swb[lane * 4] = wv4;       // overwrite sigma with wm (same lanes)
    ws = waveAllSum(ws); swz = waveAllSum(swz);
    cx = waveAllSum(cx); cy = waveAllSum(cy); cz = waveAllSum(cz);
    depth = swz / dn;
    var = 0.f;
#pragma unroll
    for (int i = 0; i < 4; i++) {
      float dd = depth - z[i] / dn;
      var = fmaf(wm[i], dd * dd, var);
    }
    var = waveAllSum(var);
  }
  if (lane == 0) {
    out[OFF_DEPTH + ray] = depth;
    out[OFF_VAR + ray]   = var;
    out[OFF_COORD + ray * 3 + 0] = cx;
    out[OFF_COORD + ray * 3 + 1] = cy;
    out[OFF_COORD + ray * 3 + 2] = cz;
  }

  // ================ PHASE 2: color + clip MLPs via MFMA ======================
  float imgp = 0.f;
  float gp[4][4];
#pragma unroll
  for (int ht = 0; ht < 4; ht++)
#pragma unroll
    for (int r = 0; r < 4; r++) gp[ht][r] = 0.f;

#pragma unroll 1
  for (int mt = 0; mt < 16; mt++) {
    const int s = mt * 16 + c16;
    bf16x8 gfr = zf;
    if (o == 0)      gfr = *(bf16x8*)&geoA[wave][s][0];
    else if (o == 1) gfr = *(bf16x8*)&geoB[wave][s][0];
    const float wmv = swb[s];
    // ---- B1a ----
    bf16x8 bfr1 = (o == 2) ? dfr : gfr;
    float r0 = 0.f, r1 = 0.f, r2 = 0.f;
#pragma unroll
    for (int ht = 0; ht < 4; ht++) {
      f32x4 hc = MFMA(c1a[ht], bfr1, *(f32x4*)&sBc1[16 * ht + 4 * o]);
#pragma unroll
      for (int r = 0; r < 4; r++) {
        float hv = fmaxf(hc[r], 0.f);
        float4 w2 = wc2s[16 * ht + 4 * o + r];
        r0 = fmaf(hv, w2.x, r0); r1 = fmaf(hv, w2.y, r1); r2 = fmaf(hv, w2.z, r2);
      }
    }
    r0 += __shfl_xor(r0, 16, 64); r0 += __shfl_xor(r0, 32, 64);
    r1 += __shfl_xor(r1, 16, 64); r1 += __shfl_xor(r1, 32, 64);
    r2 += __shfl_xor(r2, 16, 64); r2 += __shfl_xor(r2, 32, 64);
    // ---- B1b epilogue ----
    {
      float rq = (o == 0) ? (r0 + bc2[0]) : ((o == 1) ? (r1 + bc2[1]) : (r2 + bc2[2]));
      float sgd = __builtin_amdgcn_rcpf(1.f + __expf(-rq));
      sgd = (wmv > 0.f) ? sgd : 0.f;
      if (o < 3) {
        out[OFF_RGBS + ((long)ray * 256 + s) * 3 + o] = sgd;
        imgp = fmaf(wmv, sgd, imgp);
      }
    }
    // ---- B2a ----
#pragma unroll
    for (int ht = 0; ht < 4; ht++) {
      f32x4 hk = MFMA(k1a[ht], gfr, *(f32x4*)&sBk1[16 * ht + 4 * o]);
#pragma unroll
      for (int r = 0; r < 4; r++)
        gp[ht][r] = fmaf(wmv, fmaxf(hk[r], 0.f), gp[ht][r]);
    }
  }

  // image: reduce within o-group (channel partials), then pick group sums
  imgp += __shfl_xor(imgp, 1, 64);
  imgp += __shfl_xor(imgp, 2, 64);
  imgp += __shfl_xor(imgp, 4, 64);
  imgp += __shfl_xor(imgp, 8, 64);
  {
    float img0 = __shfl(imgp, 0, 64);
    float img1 = __shfl(imgp, 16, 64);
    float img2 = __shfl(imgp, 32, 64);
    if (lane == 0) {
      out[OFF_IMG + ray * 3 + 0] = img0 + (1.f - ws);
      out[OFF_IMG + ray * 3 + 1] = img1 + (1.f - ws);
      out[OFF_IMG + ray * 3 + 2] = img2 + (1.f - ws);
    }
  }

  // ---- B2b: reduce g over samples, then clip = g @ Wk2 + ws*bk2 ----
#pragma unroll
  for (int ht = 0; ht < 4; ht++)
#pragma unroll
    for (int r = 0; r < 4; r++) {
      float g = gp[ht][r];
      g += __shfl_xor(g, 1, 64); g += __shfl_xor(g, 2, 64);
      g += __shfl_xor(g, 4, 64); g += __shfl_xor(g, 8, 64);
      gp[ht][r] = g;                 // g[h], h = 16*ht + 4*o + r
    }
  {
    const int k2 = 2 * c16;
    float cp0 = 0.f, cp1 = 0.f;
#pragma unroll
    for (int ht = 0; ht < 4; ht++)
#pragma unroll
      for (int r = 0; r < 4; r++) {
        int h = 16 * ht + 4 * o + r;
        cp0 = fmaf(gp[ht][r], Wk2[h * 32 + k2], cp0);
        cp1 = fmaf(gp[ht][r], Wk2[h * 32 + k2 + 1], cp1);
      }
    cp0 += __shfl_xor(cp0, 16, 64); cp0 += __shfl_xor(cp0, 32, 64);
    cp1 += __shfl_xor(cp1, 16, 64); cp1 += __shfl_xor(cp1, 32, 64);
    cp0 = fmaf(ws, bk2[k2], cp0);
    cp1 = fmaf(ws, bk2[k2 + 1], cp1);
    if (lane < 16) {
      out[OFF_CLIP + ray * 32 + k2]     = cp0;
      out[OFF_CLIP + ray * 32 + k2 + 1] = cp1;
    }
  }
}

extern "C" void kernel_launch(void* const* d_in, const int* in_sizes, int n_in,
                              void* d_out, int out_size, void* d_ws, size_t ws_size,
                              hipStream_t stream) {
  const bool prep = (ws_size >= 10240);
  if (prep) {
    prep_kernel<<<1, 64, 0, stream>>>((fpp)d_in[5], (fpp)d_in[7], (fpp)d_in[11],
                                      (uint4*)d_ws);
    nerf_kernel<true><<<NRAYS / 4, 256, 0, stream>>>(
        (fpp)d_in[0], (fpp)d_in[1], (fpp)d_in[2],
        (fpp)d_in[3], (fpp)d_in[4], (fpp)d_in[5], (fpp)d_in[6],
        (fpp)d_in[7], (fpp)d_in[8], (fpp)d_in[9], (fpp)d_in[10],
        (fpp)d_in[11], (fpp)d_in[12], (fpp)d_in[13], (fpp)d_in[14],
        (const uint4*)d_ws, (float*)d_out);
  } else {
    nerf_kernel<false><<<NRAYS / 4, 256, 0, stream>>>(
        (fpp)d_in[0], (fpp)d_in[1], (fpp)d_in[2],
        (fpp)d_in[3], (fpp)d_in[4], (fpp)d_in[5], (fpp)d_in[6],
        (fpp)d_in[7], (fpp)d_in[8], (fpp)d_in[9], (fpp)d_in[10],
        (fpp)d_in[11], (fpp)d_in[12], (fpp)d_in[13], (fpp)d_in[14],
        (const uint4*)d_ws, (float*)d_out);
  }
}